// Round 8
// baseline (636.083 us; speedup 1.0000x reference)
//
#include <hip/hip_runtime.h>
#include <math.h>

// FusionNeRF round 10:
//   - r9 post-mortem: depth-2 at 4-frag granularity spilled (WRITE 6.8->76MB,
//     VGPR stuck 84) -> +20us. Register footprint, not protocol, was the blocker.
//   - r10: 512-thread / 8-wave blocks, wave = 32 feats x 64 samples. Halves
//     per-wave footprint (acc 32 AGPR, 2 W-frags/k-slice) -> fits 4 waves/SIMD
//     (launch_bounds(512,4), 2 blocks/CU, LDS unchanged) AND depth-2 weight
//     prefetch (wa[3][2]=24 regs < r8's wa[2][4]=32). Validated self-contained
//     counted-wait protocol preserved: nothing in flight crosses plain-C code.

#define RAYS 2048
#define SAMP 128
#define MTOT (RAYS * SAMP)
#define HD   256
#define BM   64              // samples per block
#define ES   136             // enc LDS stride (bf16), Kpad=128 (+8 pad, 272B rows)
#define HS   264             // hidden LDS stride (bf16), 256 (+8 pad, 528B rows)

// output float offsets
#define OUT_RGB   0
#define OUT_DEPTH 6144
#define OUT_W     8192
#define OUT_SW    270336
#define OUT_DW    532480

// bf16 weight workspace offsets (elements)
#define SW0 0
#define SW1 32768
#define SW2 98304
#define SW3 163840
#define SW4 229376
#define DW0 233472
#define DW1 266240
#define DW2 331776
#define DW3 397312
#define DW4 462848
#define WTOT 466944

typedef __attribute__((ext_vector_type(8))) short short8;
typedef __attribute__((ext_vector_type(4))) float f32x4;
typedef __attribute__((ext_vector_type(2))) unsigned int uint2v;

__device__ __forceinline__ float sigm(float x) { return 1.0f / (1.0f + expf(-x)); }

__device__ __forceinline__ short f2bf(float f) {   // RNE fp32 -> bf16
    union { float f; unsigned u; } v; v.f = f;
    unsigned r = v.u + 0x7fffu + ((v.u >> 16) & 1u);
    return (short)(r >> 16);
}

// Unmovable memory ops (volatile asm). Counted waits + sched_barrier(0) (rule #18).
#define GLB_LOAD(dst, ptr, imm) \
    asm volatile("global_load_dwordx4 %0, %1, off offset:%c2" \
                 : "=v"(dst) : "v"(ptr), "n"(imm))
#define LDS_READ(dst, addr, imm) \
    asm volatile("ds_read_b128 %0, %1 offset:%c2" \
                 : "=v"(dst) : "v"(addr), "n"(imm))
#define WAITCNT(vm, lg) do { \
    asm volatile("s_waitcnt vmcnt(%c0) lgkmcnt(%c1)" :: "n"(vm), "n"(lg)); \
    __builtin_amdgcn_sched_barrier(0); } while (0)

// Barrier with LDS drain only (validated r5/r8).
__device__ __forceinline__ void bar_lgkm() {
    __builtin_amdgcn_sched_barrier(0);
    asm volatile("s_waitcnt lgkmcnt(0)\n\ts_barrier" ::: "memory");
    __builtin_amdgcn_sched_barrier(0);
}
// Ordering-only barrier (all reads already drained via counted waits).
__device__ __forceinline__ void bar_only() {
    __builtin_amdgcn_sched_barrier(0);
    asm volatile("s_barrier" ::: "memory");
    __builtin_amdgcn_sched_barrier(0);
}

// ---------------- weight prep: W[K][N] fp32 -> Wt[Npad][Kpad] bf16 ----------------
__device__ __forceinline__ void conv1(const float* __restrict__ src, short* __restrict__ dst,
                                      int local, int K, int N, int Kpad) {
    const int n = local / Kpad, k = local - n * Kpad;
    const float v = (k < K && n < N) ? src[k * N + n] : 0.0f;
    dst[local] = f2bf(v);
}

__global__ __launch_bounds__(256)
void prep_weights(const float* sW0, const float* sW1, const float* sW2,
                  const float* sW3, const float* sW4,
                  const float* dW0, const float* dW1, const float* dW2,
                  const float* dW3, const float* dW4, short* __restrict__ dst)
{
    const int idx = blockIdx.x * 256 + threadIdx.x;
    if (idx >= WTOT) return;
    if      (idx < SW1) conv1(sW0, dst + SW0, idx - SW0,  90, 256, 128);
    else if (idx < SW2) conv1(sW1, dst + SW1, idx - SW1, 256, 256, 256);
    else if (idx < SW3) conv1(sW2, dst + SW2, idx - SW2, 256, 256, 256);
    else if (idx < SW4) conv1(sW3, dst + SW3, idx - SW3, 256, 256, 256);
    else if (idx < DW0) conv1(sW4, dst + SW4, idx - SW4, 256,   4, 256);
    else if (idx < DW1) conv1(dW0, dst + DW0, idx - DW0,  99, 256, 128);
    else if (idx < DW2) conv1(dW1, dst + DW1, idx - DW1, 256, 256, 256);
    else if (idx < DW3) conv1(dW2, dst + DW2, idx - DW2, 256, 256, 256);
    else if (idx < DW4) conv1(dW3, dst + DW3, idx - DW3, 256, 256, 256);
    else                conv1(dW4, dst + DW4, idx - DW4, 256,   5, 256);
}

// ---------------- MFMA dense layer: 8 waves x (32 feat x 64 samp), depth-2 W ----
// A-operand = weights Wt[256][K] (global, L2-hot), B-operand = acts [64][AS] (LDS).
// Wave w owns features [32w, 32w+32) as 2 ft-frags. Depth-2 weight prefetch
// (wa[3][2]), depth-1 act prefetch (ba[2][4]). Self-contained: last k-step
// drains (0,0); no in-flight asm load crosses plain-C code.
// Entry:  W0,W1,W2 (6 GLB) + A0,A1 (8 LDS); wait (4,4) -> k0 ready.
// Steady (1 <= kk <= KS-3): issue W(kk+2) (2), A(kk+1) (4); wait (4,4).
// kk == KS-2: issue A(kk+1) (4); wait (2,4).
// kk == KS-1: wait (0,0).
template <int KSTEPS, bool RELU, int AS>
__device__ __forceinline__ void layer256(const short* A,
                                         const short* __restrict__ Wt,
                                         const float* __restrict__ bias,
                                         short* O, int Os, int tid)
{
    const int w = tid >> 6, lane = tid & 63, qq = lane >> 4, col = lane & 15;
    constexpr int K = KSTEPS * 32;
    static_assert(KSTEPS >= 4, "pipeline depth assumes KSTEPS >= 4");

    const short* wp0 = Wt + (size_t)(w * 32 +  0 + col) * K + qq * 8;
    const short* wp1 = Wt + (size_t)(w * 32 + 16 + col) * K + qq * 8;
    // LDS byte address (generic shared addr: low 32 bits are the LDS offset)
    const unsigned ab = (unsigned)(size_t)(const void*)A + (unsigned)((col * AS + qq * 8) * 2);

    short8 wa[3][2], ba[2][4];   // all indices compile-time after full unroll

    // entry: weights k0,k1,k2 (longest latency first), then acts k0,k1
    GLB_LOAD(wa[0][0], wp0, 0);
    GLB_LOAD(wa[0][1], wp1, 0);
    GLB_LOAD(wa[1][0], wp0, 64);
    GLB_LOAD(wa[1][1], wp1, 64);
    GLB_LOAD(wa[2][0], wp0, 128);
    GLB_LOAD(wa[2][1], wp1, 128);
    LDS_READ(ba[0][0], ab, (0 * 16 * AS) * 2);
    LDS_READ(ba[0][1], ab, (1 * 16 * AS) * 2);
    LDS_READ(ba[0][2], ab, (2 * 16 * AS) * 2);
    LDS_READ(ba[0][3], ab, (3 * 16 * AS) * 2);
    LDS_READ(ba[1][0], ab, (0 * 16 * AS) * 2 + 64);
    LDS_READ(ba[1][1], ab, (1 * 16 * AS) * 2 + 64);
    LDS_READ(ba[1][2], ab, (2 * 16 * AS) * 2 + 64);
    LDS_READ(ba[1][3], ab, (3 * 16 * AS) * 2 + 64);
    WAITCNT(4, 4);   // W0,A0 ready; W1,W2 + A1 flying

    f32x4 acc[2][4];
#pragma unroll
    for (int ft = 0; ft < 2; ft++)
#pragma unroll
        for (int st = 0; st < 4; st++) acc[ft][st] = (f32x4)0.0f;

#pragma unroll
    for (int kk = 0; kk < KSTEPS; kk++) {
        const int c3 = kk % 3, c2 = kk & 1;
        if (kk >= 1 && kk <= KSTEPS - 3) {
            const int w3 = (kk + 2) % 3, a2 = (kk + 1) & 1;
            GLB_LOAD(wa[w3][0], wp0, (kk + 2) * 64);
            GLB_LOAD(wa[w3][1], wp1, (kk + 2) * 64);
            LDS_READ(ba[a2][0], ab, (0 * 16 * AS) * 2 + (kk + 1) * 64);
            LDS_READ(ba[a2][1], ab, (1 * 16 * AS) * 2 + (kk + 1) * 64);
            LDS_READ(ba[a2][2], ab, (2 * 16 * AS) * 2 + (kk + 1) * 64);
            LDS_READ(ba[a2][3], ab, (3 * 16 * AS) * 2 + (kk + 1) * 64);
            WAITCNT(4, 4);                 // W(kk)/A(kk) ready; 2 W-sets + 1 A-set flying
        } else if (kk == KSTEPS - 2) {
            const int a2 = (kk + 1) & 1;
            LDS_READ(ba[a2][0], ab, (0 * 16 * AS) * 2 + (kk + 1) * 64);
            LDS_READ(ba[a2][1], ab, (1 * 16 * AS) * 2 + (kk + 1) * 64);
            LDS_READ(ba[a2][2], ab, (2 * 16 * AS) * 2 + (kk + 1) * 64);
            LDS_READ(ba[a2][3], ab, (3 * 16 * AS) * 2 + (kk + 1) * 64);
            WAITCNT(2, 4);                 // W(kk)/A(kk) ready; last W + last A flying
        } else if (kk == KSTEPS - 1) {
            WAITCNT(0, 0);                 // drain: layer self-contained
        }
#pragma unroll
        for (int ft = 0; ft < 2; ft++)
#pragma unroll
            for (int st = 0; st < 4; st++)
                acc[ft][st] = __builtin_amdgcn_mfma_f32_16x16x32_bf16(
                    wa[c3][ft], ba[c2][st], acc[ft][st], 0, 0, 0);
    }

    bar_only();       // all 8 waves done reading A (A may alias O)

#pragma unroll
    for (int ft = 0; ft < 2; ft++) {
        const f32x4 bv = *(const f32x4*)(bias + w * 32 + ft * 16 + qq * 4);
#pragma unroll
        for (int st = 0; st < 4; st++) {
            float v0 = acc[ft][st][0] + bv[0];
            float v1 = acc[ft][st][1] + bv[1];
            float v2 = acc[ft][st][2] + bv[2];
            float v3 = acc[ft][st][3] + bv[3];
            if (RELU) {
                v0 = fmaxf(v0, 0.0f); v1 = fmaxf(v1, 0.0f);
                v2 = fmaxf(v2, 0.0f); v3 = fmaxf(v3, 0.0f);
            }
            unsigned p0, p1;   // RNE pack, matches f2bf
            asm("v_cvt_pk_bf16_f32 %0, %1, %2" : "=v"(p0) : "v"(v0), "v"(v1));
            asm("v_cvt_pk_bf16_f32 %0, %1, %2" : "=v"(p1) : "v"(v2), "v"(v3));
            uint2v pk; pk[0] = p0; pk[1] = p1;
            *(uint2v*)(O + (size_t)(st * 16 + col) * Os + w * 32 + ft * 16 + qq * 4) = pk;
        }
    }
    bar_lgkm();   // O visible to next layer
}

// head (swapped): waves 0-3 each handle 16 samples; waves 4-7 skip (no barriers
// inside). Plain C — our asm queues are empty here (layers drain).
template <int NV, int OS>
__device__ __forceinline__ void head256(const short* A, int As,
                                        const short* __restrict__ Wt,
                                        const float* __restrict__ bias,
                                        float* Out, int tid)
{
    const int w = tid >> 6, lane = tid & 63, qq = lane >> 4, col = lane & 15;
    if (w >= 4) return;
    f32x4 acc = (f32x4)0.0f;
#pragma unroll
    for (int kk = 0; kk < 8; kk++) {
        short8 a = *(const short8*)(Wt + col * 256 + kk * 32 + qq * 8);
        short8 b = *(const short8*)(A + (size_t)(w * 16 + col) * As + kk * 32 + qq * 8);
        acc = __builtin_amdgcn_mfma_f32_16x16x32_bf16(a, b, acc, 0, 0, 0);
    }
    const int s = w * 16 + col;
    if (qq == 0) {
#pragma unroll
        for (int i = 0; i < 4; i++) Out[s * OS + i] = acc[i] + bias[i];
    } else if (NV == 5 && qq == 1) {
        Out[s * OS + 4] = acc[0] + bias[4];
    }
}

__global__ __launch_bounds__(512, 4)
void nerf_mlp(const float* __restrict__ points, const float* __restrict__ dirsv,
              const float* __restrict__ timev, const short* __restrict__ wt,
              const float* __restrict__ sb0, const float* __restrict__ sb1,
              const float* __restrict__ sb2, const float* __restrict__ sb3,
              const float* __restrict__ sb4,
              const float* __restrict__ db0, const float* __restrict__ db1,
              const float* __restrict__ db2, const float* __restrict__ db3,
              const float* __restrict__ db4,
              float* __restrict__ o_sigma, float* __restrict__ o_r,
              float* __restrict__ o_g, float* __restrict__ o_b,
              float* __restrict__ o_bw)
{
    __shared__ __align__(16) short E[BM][ES];   // 17408 B
    __shared__ __align__(16) short Hb[BM][HS];  // 33792 B
    __shared__ float so[BM][4];                 //  1024 B
    __shared__ float dn[BM][5];                 //  1280 B -> 53504 B => 2 blocks/CU (16 waves)

    const int tid = threadIdx.x;
    const int m0  = blockIdx.x * BM;

    // ---- positional encoding -> E (bf16). sinf/cosf (no sincosf scratch). ----
    for (int idx = tid; idx < BM * 64; idx += 512) {
        const int s = idx >> 6, j = idx & 63, m = m0 + s;
        if (j < 46) {
            float x; int dsin, dcos;
            if (j < 30) {                       // pos: 10 bands x 3 coords
                const int l = j / 3, c = j - 3 * l;
                x = points[m * 3 + c] * (float)(1 << l);
                dsin = 3 + l * 6 + c; dcos = dsin + 3;
            } else if (j < 42) {                // dirs: 4 bands x 3 coords
                const int jj = j - 30, l = jj / 3, c = jj - 3 * l;
                x = dirsv[m * 3 + c] * (float)(1 << l);
                dsin = 66 + l * 6 + c; dcos = dsin + 3;
            } else {                            // time: 4 bands x 1
                const int l = j - 42;
                x = timev[m] * (float)(1 << l);
                dsin = 91 + 2 * l; dcos = dsin + 1;
            }
            E[s][dsin] = f2bf(sinf(x));
            E[s][dcos] = f2bf(cosf(x));
        } else {                                // passthroughs + zero pad
            int t = (j - 46) * 2;
#pragma unroll
            for (int u = 0; u < 2; u++, t++) {
                float v = 0.0f; int d;
                if (t < 3)       { d = t;        v = points[m * 3 + t]; }
                else if (t < 6)  { d = 60 + t;   v = dirsv[m * 3 + t - 3]; }  // 63..65
                else if (t == 6) { d = 90;       v = timev[m]; }
                else             { d = 92 + t; }                              // 99..127 = 0
                E[s][d] = f2bf(v);
            }
        }
    }
    bar_lgkm();

    // ---- static MLP ----
    layer256<4, true, ES>(&E[0][0],  wt + SW0, sb0, &Hb[0][0], HS, tid);
    layer256<8, true, HS>(&Hb[0][0], wt + SW1, sb1, &Hb[0][0], HS, tid);
    layer256<8, true, HS>(&Hb[0][0], wt + SW2, sb2, &Hb[0][0], HS, tid);
    layer256<8, true, HS>(&Hb[0][0], wt + SW3, sb3, &Hb[0][0], HS, tid);
    head256<4, 4>(&Hb[0][0], HS, wt + SW4, sb4, &so[0][0], tid);
    // (dynamic L0's bar_only orders these head reads of Hb vs its Hb overwrite)

    // ---- dynamic MLP ----
    layer256<4, true, ES>(&E[0][0],  wt + DW0, db0, &Hb[0][0], HS, tid);
    layer256<8, true, HS>(&Hb[0][0], wt + DW1, db1, &Hb[0][0], HS, tid);
    layer256<8, true, HS>(&Hb[0][0], wt + DW2, db2, &Hb[0][0], HS, tid);
    layer256<8, true, HS>(&Hb[0][0], wt + DW3, db3, &Hb[0][0], HS, tid);
    head256<5, 5>(&Hb[0][0], HS, wt + DW4, db4, &dn[0][0], tid);
    bar_lgkm();

    // ---- blend ----
    if (tid < BM) {
        const int s = tid, m = m0 + s;
        const float bw = sigm(dn[s][4]);
        const float sigma = (1.f - bw) * so[s][0] + bw * dn[s][0];
        const float r  = (1.f - bw) * sigm(so[s][1]) + bw * sigm(dn[s][1]);
        const float gg = (1.f - bw) * sigm(so[s][2]) + bw * sigm(dn[s][2]);
        const float bb = (1.f - bw) * sigm(so[s][3]) + bw * sigm(dn[s][3]);
        o_sigma[m] = sigma; o_r[m] = r; o_g[m] = gg; o_b[m] = bb; o_bw[m] = bw;
    }
}

// ---------------- compositing: one wave per ray, shuffle scan ----------------
__global__ __launch_bounds__(256)
void nerf_comp(const float* __restrict__ zv,
               const float* __restrict__ o_sigma, const float* __restrict__ o_r,
               const float* __restrict__ o_g, const float* __restrict__ o_b,
               const float* __restrict__ o_bw, float* __restrict__ out)
{
    const int ray  = blockIdx.x * 4 + (threadIdx.x >> 6);
    const int lane = threadIdx.x & 63;
    const int base = ray * SAMP;
    const int s0 = 2 * lane, s1 = s0 + 1;

    const float z0 = zv[base + s0];
    const float z1 = zv[base + s1];
    const float z2 = (lane < 63) ? zv[base + s1 + 1] : 0.0f;
    const float d0 = z1 - z0;
    const float d1 = (lane < 63) ? (z2 - z1) : 1e10f;

    const float sg0 = o_sigma[base + s0], sg1 = o_sigma[base + s1];
    const float a0 = 1.0f - expf(-sg0 * d0);
    const float a1 = 1.0f - expf(-sg1 * d1);
    const float f0 = 1.0f - a0 + 1e-10f;
    const float f1 = 1.0f - a1 + 1e-10f;

    float incl = f0 * f1;
#pragma unroll
    for (int dlt = 1; dlt < 64; dlt <<= 1) {
        const float t = __shfl_up(incl, dlt);
        if (lane >= dlt) incl *= t;
    }
    float ex = __shfl_up(incl, 1);
    if (lane == 0) ex = 1.0f;

    const float t0 = ex;
    const float t1 = ex * f0;
    const float w0 = a0 * t0, w1 = a1 * t1;

    const float bw0 = o_bw[base + s0], bw1 = o_bw[base + s1];
    out[OUT_W  + base + s0] = w0;               out[OUT_W  + base + s1] = w1;
    out[OUT_SW + base + s0] = (1.f - bw0) * w0; out[OUT_SW + base + s1] = (1.f - bw1) * w1;
    out[OUT_DW + base + s0] = bw0 * w0;         out[OUT_DW + base + s1] = bw1 * w1;

    float pr = w0 * o_r[base + s0] + w1 * o_r[base + s1];
    float pg = w0 * o_g[base + s0] + w1 * o_g[base + s1];
    float pb = w0 * o_b[base + s0] + w1 * o_b[base + s1];
    float pd = w0 * z0 + w1 * z1;
#pragma unroll
    for (int dlt = 32; dlt >= 1; dlt >>= 1) {
        pr += __shfl_down(pr, dlt);
        pg += __shfl_down(pg, dlt);
        pb += __shfl_down(pb, dlt);
        pd += __shfl_down(pd, dlt);
    }
    if (lane == 0) {
        out[OUT_RGB + ray * 3 + 0] = pr;
        out[OUT_RGB + ray * 3 + 1] = pg;
        out[OUT_RGB + ray * 3 + 2] = pb;
        out[OUT_DEPTH + ray] = pd;
    }
}

extern "C" void kernel_launch(void* const* d_in, const int* in_sizes, int n_in,
                              void* d_out, int out_size, void* d_ws, size_t ws_size,
                              hipStream_t stream)
{
    const float* points = (const float*)d_in[0];
    const float* dirsv  = (const float*)d_in[1];
    const float* zvals  = (const float*)d_in[2];
    const float* timev  = (const float*)d_in[3];

    const float *sW[5], *sb[5], *dW[5], *db[5];
    if (in_sizes[6] == 99 * 256) {
        for (int i = 0; i < 5; i++) {   // interleaved (sW_i, sb_i, dW_i, db_i)
            sW[i] = (const float*)d_in[4 + 4 * i + 0];
            sb[i] = (const float*)d_in[4 + 4 * i + 1];
            dW[i] = (const float*)d_in[4 + 4 * i + 2];
            db[i] = (const float*)d_in[4 + 4 * i + 3];
        }
    } else {
        for (int i = 0; i < 5; i++) {   // all static then all dynamic
            sW[i] = (const float*)d_in[4 + 2 * i + 0];
            sb[i] = (const float*)d_in[4 + 2 * i + 1];
            dW[i] = (const float*)d_in[14 + 2 * i + 0];
            db[i] = (const float*)d_in[14 + 2 * i + 1];
        }
    }

    // ws layout: bf16 weights (933888 B) then 5 fp32 per-sample arrays (1 MB each)
    short* wt = (short*)d_ws;
    float* ws = (float*)((char*)d_ws + (size_t)WTOT * 2);
    float* o_sigma = ws;
    float* o_r  = ws + (size_t)MTOT * 1;
    float* o_g  = ws + (size_t)MTOT * 2;
    float* o_b  = ws + (size_t)MTOT * 3;
    float* o_bw = ws + (size_t)MTOT * 4;

    prep_weights<<<(WTOT + 255) / 256, 256, 0, stream>>>(
        sW[0], sW[1], sW[2], sW[3], sW[4], dW[0], dW[1], dW[2], dW[3], dW[4], wt);

    nerf_mlp<<<MTOT / BM, 512, 0, stream>>>(points, dirsv, timev, wt,
        sb[0], sb[1], sb[2], sb[3], sb[4], db[0], db[1], db[2], db[3], db[4],
        o_sigma, o_r, o_g, o_b, o_bw);

    nerf_comp<<<RAYS / 4, 256, 0, stream>>>(zvals, o_sigma, o_r, o_g, o_b, o_bw,
                                            (float*)d_out);
}

// Round 9
// 626.438 us; speedup vs baseline: 1.0154x; 1.0154x over previous
//
#include <hip/hip_runtime.h>
#include <math.h>

// FusionNeRF round 11:
//   - r9/r10 post-mortem: both latency-hiding swings washed. r10: +37% occupancy
//     eaten by 1.33x LDS traffic + 58% more bank conflicts (8 waves redundantly
//     reading the same acts); halved k-step halved the latency cover. r8's shape
//     (4 waves x 64ft, depth-1) is the balanced point -> revert to it (555us).
//   - This round, guaranteed wins: (1) prep_weights was 1KB-strided uncoalesced
//     (~16x overfetch, ~25us of the 59us bench-vs-mlp gap) -> LDS-transpose
//     rewrite, coalesced both sides; (2) static L0 skips the alias barrier
//     (E -> Hb, no alias); (3) s_setprio(1) around MFMA cluster (T5; cross-block
//     waves are phase-diverse -> the regime where it paid).

#define RAYS 2048
#define SAMP 128
#define MTOT (RAYS * SAMP)
#define HD   256
#define BM   64              // samples per block
#define ES   136             // enc LDS stride (bf16), Kpad=128 (+8 pad, 272B rows)
#define HS   264             // hidden LDS stride (bf16), 256 (+8 pad, 528B rows)

// output float offsets
#define OUT_RGB   0
#define OUT_DEPTH 6144
#define OUT_W     8192
#define OUT_SW    270336
#define OUT_DW    532480

// bf16 weight workspace offsets (elements)
#define SW0 0
#define SW1 32768
#define SW2 98304
#define SW3 163840
#define SW4 229376
#define DW0 233472
#define DW1 266240
#define DW2 331776
#define DW3 397312
#define DW4 462848
#define WTOT 466944

typedef __attribute__((ext_vector_type(8))) short short8;
typedef __attribute__((ext_vector_type(4))) float f32x4;
typedef __attribute__((ext_vector_type(2))) unsigned int uint2v;

__device__ __forceinline__ float sigm(float x) { return 1.0f / (1.0f + expf(-x)); }

__device__ __forceinline__ short f2bf(float f) {   // RNE fp32 -> bf16
    union { float f; unsigned u; } v; v.f = f;
    unsigned r = v.u + 0x7fffu + ((v.u >> 16) & 1u);
    return (short)(r >> 16);
}

// Unmovable memory ops (volatile asm). Counted waits + sched_barrier(0) (rule #18).
#define GLB_LOAD(dst, ptr, imm) \
    asm volatile("global_load_dwordx4 %0, %1, off offset:%c2" \
                 : "=v"(dst) : "v"(ptr), "n"(imm))
#define LDS_READ(dst, addr, imm) \
    asm volatile("ds_read_b128 %0, %1 offset:%c2" \
                 : "=v"(dst) : "v"(addr), "n"(imm))
#define WAITCNT(vm, lg) do { \
    asm volatile("s_waitcnt vmcnt(%c0) lgkmcnt(%c1)" :: "n"(vm), "n"(lg)); \
    __builtin_amdgcn_sched_barrier(0); } while (0)

// Barrier with LDS drain only (validated r5/r8).
__device__ __forceinline__ void bar_lgkm() {
    __builtin_amdgcn_sched_barrier(0);
    asm volatile("s_waitcnt lgkmcnt(0)\n\ts_barrier" ::: "memory");
    __builtin_amdgcn_sched_barrier(0);
}
// Ordering-only barrier (all reads already drained via counted waits).
__device__ __forceinline__ void bar_only() {
    __builtin_amdgcn_sched_barrier(0);
    asm volatile("s_barrier" ::: "memory");
    __builtin_amdgcn_sched_barrier(0);
}

// ---------------- weight prep: LDS-transpose, coalesced both sides --------------
// 34 blocks, one per (matrix, 64-col n-tile). Read: coalesced src rows ->
// T[nn][k] (stride 258 shorts = odd dwords, conflict-free). Write: k-contiguous
// coalesced bf16 rows. Tail mats (N=4/5) write their full 16-row padded region
// (T rows >= N are zeros via the read guard), matching the old layout exactly.
__global__ __launch_bounds__(256)
void prep_weights(const float* sW0, const float* sW1, const float* sW2,
                  const float* sW3, const float* sW4,
                  const float* dW0, const float* dW1, const float* dW2,
                  const float* dW3, const float* dW4, short* __restrict__ dst)
{
    const int b = blockIdx.x, tid = threadIdx.x;
    const float* src; int K, N, Kpad, n0, Nw; size_t doff;
    if      (b <  4) { src = sW0; K =  90; N = 256; Kpad = 128; doff = SW0; n0 = b * 64;        Nw = 64; }
    else if (b <  8) { src = sW1; K = 256; N = 256; Kpad = 256; doff = SW1; n0 = (b - 4) * 64;  Nw = 64; }
    else if (b < 12) { src = sW2; K = 256; N = 256; Kpad = 256; doff = SW2; n0 = (b - 8) * 64;  Nw = 64; }
    else if (b < 16) { src = sW3; K = 256; N = 256; Kpad = 256; doff = SW3; n0 = (b - 12) * 64; Nw = 64; }
    else if (b == 16){ src = sW4; K = 256; N =   4; Kpad = 256; doff = SW4; n0 = 0;             Nw = 16; }
    else if (b < 21) { src = dW0; K =  99; N = 256; Kpad = 128; doff = DW0; n0 = (b - 17) * 64; Nw = 64; }
    else if (b < 25) { src = dW1; K = 256; N = 256; Kpad = 256; doff = DW1; n0 = (b - 21) * 64; Nw = 64; }
    else if (b < 29) { src = dW2; K = 256; N = 256; Kpad = 256; doff = DW2; n0 = (b - 25) * 64; Nw = 64; }
    else if (b < 33) { src = dW3; K = 256; N = 256; Kpad = 256; doff = DW3; n0 = (b - 29) * 64; Nw = 64; }
    else             { src = dW4; K = 256; N =   5; Kpad = 256; doff = DW4; n0 = 0;             Nw = 16; }

    __shared__ short T[64][258];   // 33,024 B; odd-dword row stride -> conflict-free

    for (int idx = tid; idx < Kpad * 64; idx += 256) {    // coalesced over nn
        const int k = idx >> 6, nn = idx & 63;
        const float v = (k < K && n0 + nn < N) ? src[k * N + n0 + nn] : 0.0f;
        T[nn][k] = f2bf(v);
    }
    __syncthreads();

    const int ks = (Kpad == 128) ? 7 : 8;
    for (int idx = tid; idx < Nw * Kpad; idx += 256) {    // coalesced over k
        const int n = idx >> ks, k = idx & (Kpad - 1);
        dst[doff + (size_t)(n0 + n) * Kpad + k] = T[n][k];
    }
}

// ---------------- MFMA dense layer: self-contained asm k-pipeline (r8) ----------
// A-operand = weights Wt[256][K] (global, L2-hot), B-operand = acts [64][AS] (LDS).
// Entry: issue k0+k1 weights (GLB) + k0+k1 acts (LDS), wait (4,4).
// Steady: issue kk+1 (4 GLB + 4 LDS), wait (4,4). Last: wait (0,0) — layer
// self-contained; nothing in flight crosses plain-C code.
// BAR1: emit the pre-epilogue alias barrier (false when A and O don't alias).
template <int KSTEPS, bool RELU, int AS, bool BAR1 = true>
__device__ __forceinline__ void layer256(const short* A,
                                         const short* __restrict__ Wt,
                                         const float* __restrict__ bias,
                                         short* O, int Os, int tid)
{
    const int w = tid >> 6, lane = tid & 63, qq = lane >> 4, col = lane & 15;
    constexpr int K = KSTEPS * 32;

    const short* wp0 = Wt + (size_t)(w * 64 +  0 + col) * K + qq * 8;
    const short* wp1 = Wt + (size_t)(w * 64 + 16 + col) * K + qq * 8;
    const short* wp2 = Wt + (size_t)(w * 64 + 32 + col) * K + qq * 8;
    const short* wp3 = Wt + (size_t)(w * 64 + 48 + col) * K + qq * 8;
    // LDS byte address (generic shared addr: low 32 bits are the LDS offset)
    const unsigned ab = (unsigned)(size_t)(const void*)A + (unsigned)((col * AS + qq * 8) * 2);

    short8 wa[2][4], ba[2][4];   // ping-pong, all indices compile-time after unroll

    GLB_LOAD(wa[0][0], wp0, 0);
    GLB_LOAD(wa[0][1], wp1, 0);
    GLB_LOAD(wa[0][2], wp2, 0);
    GLB_LOAD(wa[0][3], wp3, 0);
    GLB_LOAD(wa[1][0], wp0, 64);
    GLB_LOAD(wa[1][1], wp1, 64);
    GLB_LOAD(wa[1][2], wp2, 64);
    GLB_LOAD(wa[1][3], wp3, 64);
    LDS_READ(ba[0][0], ab, (0 * 16 * AS) * 2);
    LDS_READ(ba[0][1], ab, (1 * 16 * AS) * 2);
    LDS_READ(ba[0][2], ab, (2 * 16 * AS) * 2);
    LDS_READ(ba[0][3], ab, (3 * 16 * AS) * 2);
    LDS_READ(ba[1][0], ab, (0 * 16 * AS) * 2 + 64);
    LDS_READ(ba[1][1], ab, (1 * 16 * AS) * 2 + 64);
    LDS_READ(ba[1][2], ab, (2 * 16 * AS) * 2 + 64);
    LDS_READ(ba[1][3], ab, (3 * 16 * AS) * 2 + 64);
    WAITCNT(4, 4);   // k0 weights+acts ready; k1 in flight

    f32x4 acc[4][4];
#pragma unroll
    for (int ft = 0; ft < 4; ft++)
#pragma unroll
        for (int st = 0; st < 4; st++) acc[ft][st] = (f32x4)0.0f;

#pragma unroll
    for (int kk = 0; kk < KSTEPS; kk++) {
        const int c = kk & 1, nx = c ^ 1;
        if (kk > 0 && kk < KSTEPS - 1) {
            GLB_LOAD(wa[nx][0], wp0, (kk + 1) * 64);
            GLB_LOAD(wa[nx][1], wp1, (kk + 1) * 64);
            GLB_LOAD(wa[nx][2], wp2, (kk + 1) * 64);
            GLB_LOAD(wa[nx][3], wp3, (kk + 1) * 64);
            LDS_READ(ba[nx][0], ab, (0 * 16 * AS) * 2 + (kk + 1) * 64);
            LDS_READ(ba[nx][1], ab, (1 * 16 * AS) * 2 + (kk + 1) * 64);
            LDS_READ(ba[nx][2], ab, (2 * 16 * AS) * 2 + (kk + 1) * 64);
            LDS_READ(ba[nx][3], ab, (3 * 16 * AS) * 2 + (kk + 1) * 64);
            WAITCNT(4, 4);                 // wa[kk]/ba[kk] ready; kk+1 in flight
        } else if (kk == KSTEPS - 1) {
            WAITCNT(0, 0);                 // drain: layer self-contained
        }
        __builtin_amdgcn_s_setprio(1);     // T5: favor MFMA cluster vs phase-diverse siblings
#pragma unroll
        for (int ft = 0; ft < 4; ft++)
#pragma unroll
            for (int st = 0; st < 4; st++)
                acc[ft][st] = __builtin_amdgcn_mfma_f32_16x16x32_bf16(
                    wa[c][ft], ba[c][st], acc[ft][st], 0, 0, 0);
        __builtin_amdgcn_s_setprio(0);
    }

    if (BAR1) bar_only();   // waves done reading A (needed only when A aliases O)

#pragma unroll
    for (int ft = 0; ft < 4; ft++) {
        const f32x4 bv = *(const f32x4*)(bias + w * 64 + ft * 16 + qq * 4);
#pragma unroll
        for (int st = 0; st < 4; st++) {
            float v0 = acc[ft][st][0] + bv[0];
            float v1 = acc[ft][st][1] + bv[1];
            float v2 = acc[ft][st][2] + bv[2];
            float v3 = acc[ft][st][3] + bv[3];
            if (RELU) {
                v0 = fmaxf(v0, 0.0f); v1 = fmaxf(v1, 0.0f);
                v2 = fmaxf(v2, 0.0f); v3 = fmaxf(v3, 0.0f);
            }
            unsigned p0, p1;   // RNE pack, matches f2bf
            asm("v_cvt_pk_bf16_f32 %0, %1, %2" : "=v"(p0) : "v"(v0), "v"(v1));
            asm("v_cvt_pk_bf16_f32 %0, %1, %2" : "=v"(p1) : "v"(v2), "v"(v3));
            uint2v pk; pk[0] = p0; pk[1] = p1;
            *(uint2v*)(O + (size_t)(st * 16 + col) * Os + w * 64 + ft * 16 + qq * 4) = pk;
        }
    }
    bar_lgkm();   // O visible to next layer
}

// head (swapped): A-op = head weights Wt[16][256], B-op = acts of wave's 16 samples.
// Plain C — our asm queues are empty here (layers drain), compiler accounting exact.
template <int NV, int OS>
__device__ __forceinline__ void head256(const short* A, int As,
                                        const short* __restrict__ Wt,
                                        const float* __restrict__ bias,
                                        float* Out, int tid)
{
    const int w = tid >> 6, lane = tid & 63, qq = lane >> 4, col = lane & 15;
    f32x4 acc = (f32x4)0.0f;
#pragma unroll
    for (int kk = 0; kk < 8; kk++) {
        short8 a = *(const short8*)(Wt + col * 256 + kk * 32 + qq * 8);
        short8 b = *(const short8*)(A + (size_t)(w * 16 + col) * As + kk * 32 + qq * 8);
        acc = __builtin_amdgcn_mfma_f32_16x16x32_bf16(a, b, acc, 0, 0, 0);
    }
    const int s = w * 16 + col;
    if (qq == 0) {
#pragma unroll
        for (int i = 0; i < 4; i++) Out[s * OS + i] = acc[i] + bias[i];
    } else if (NV == 5 && qq == 1) {
        Out[s * OS + 4] = acc[0] + bias[4];
    }
}

__global__ __launch_bounds__(256, 3)
void nerf_mlp(const float* __restrict__ points, const float* __restrict__ dirsv,
              const float* __restrict__ timev, const short* __restrict__ wt,
              const float* __restrict__ sb0, const float* __restrict__ sb1,
              const float* __restrict__ sb2, const float* __restrict__ sb3,
              const float* __restrict__ sb4,
              const float* __restrict__ db0, const float* __restrict__ db1,
              const float* __restrict__ db2, const float* __restrict__ db3,
              const float* __restrict__ db4,
              float* __restrict__ o_sigma, float* __restrict__ o_r,
              float* __restrict__ o_g, float* __restrict__ o_b,
              float* __restrict__ o_bw)
{
    __shared__ __align__(16) short E[BM][ES];   // 17408 B
    __shared__ __align__(16) short Hb[BM][HS];  // 33792 B
    __shared__ float so[BM][4];                 //  1024 B
    __shared__ float dn[BM][5];                 //  1280 B -> 53504 B => 3 blocks/CU

    const int tid = threadIdx.x;
    const int m0  = blockIdx.x * BM;

    // ---- positional encoding -> E (bf16). sinf/cosf (no sincosf scratch). ----
    for (int idx = tid; idx < BM * 64; idx += 256) {
        const int s = idx >> 6, j = idx & 63, m = m0 + s;
        if (j < 46) {
            float x; int dsin, dcos;
            if (j < 30) {                       // pos: 10 bands x 3 coords
                const int l = j / 3, c = j - 3 * l;
                x = points[m * 3 + c] * (float)(1 << l);
                dsin = 3 + l * 6 + c; dcos = dsin + 3;
            } else if (j < 42) {                // dirs: 4 bands x 3 coords
                const int jj = j - 30, l = jj / 3, c = jj - 3 * l;
                x = dirsv[m * 3 + c] * (float)(1 << l);
                dsin = 66 + l * 6 + c; dcos = dsin + 3;
            } else {                            // time: 4 bands x 1
                const int l = j - 42;
                x = timev[m] * (float)(1 << l);
                dsin = 91 + 2 * l; dcos = dsin + 1;
            }
            E[s][dsin] = f2bf(sinf(x));
            E[s][dcos] = f2bf(cosf(x));
        } else {                                // passthroughs + zero pad
            int t = (j - 46) * 2;
#pragma unroll
            for (int u = 0; u < 2; u++, t++) {
                float v = 0.0f; int d;
                if (t < 3)       { d = t;        v = points[m * 3 + t]; }
                else if (t < 6)  { d = 60 + t;   v = dirsv[m * 3 + t - 3]; }  // 63..65
                else if (t == 6) { d = 90;       v = timev[m]; }
                else             { d = 92 + t; }                              // 99..127 = 0
                E[s][d] = f2bf(v);
            }
        }
    }
    bar_lgkm();

    // ---- static MLP ----
    layer256<4, true, ES, false>(&E[0][0],  wt + SW0, sb0, &Hb[0][0], HS, tid);  // E->Hb: no alias
    layer256<8, true, HS>(&Hb[0][0], wt + SW1, sb1, &Hb[0][0], HS, tid);
    layer256<8, true, HS>(&Hb[0][0], wt + SW2, sb2, &Hb[0][0], HS, tid);
    layer256<8, true, HS>(&Hb[0][0], wt + SW3, sb3, &Hb[0][0], HS, tid);
    head256<4, 4>(&Hb[0][0], HS, wt + SW4, sb4, &so[0][0], tid);
    // (dynamic L0's bar_only orders these head reads of Hb vs its Hb overwrite)

    // ---- dynamic MLP ----
    layer256<4, true, ES>(&E[0][0],  wt + DW0, db0, &Hb[0][0], HS, tid);  // keeps BAR1
    layer256<8, true, HS>(&Hb[0][0], wt + DW1, db1, &Hb[0][0], HS, tid);
    layer256<8, true, HS>(&Hb[0][0], wt + DW2, db2, &Hb[0][0], HS, tid);
    layer256<8, true, HS>(&Hb[0][0], wt + DW3, db3, &Hb[0][0], HS, tid);
    head256<5, 5>(&Hb[0][0], HS, wt + DW4, db4, &dn[0][0], tid);
    bar_lgkm();

    // ---- blend ----
    if (tid < BM) {
        const int s = tid, m = m0 + s;
        const float bw = sigm(dn[s][4]);
        const float sigma = (1.f - bw) * so[s][0] + bw * dn[s][0];
        const float r  = (1.f - bw) * sigm(so[s][1]) + bw * sigm(dn[s][1]);
        const float gg = (1.f - bw) * sigm(so[s][2]) + bw * sigm(dn[s][2]);
        const float bb = (1.f - bw) * sigm(so[s][3]) + bw * sigm(dn[s][3]);
        o_sigma[m] = sigma; o_r[m] = r; o_g[m] = gg; o_b[m] = bb; o_bw[m] = bw;
    }
}

// ---------------- compositing: one wave per ray, shuffle scan ----------------
__global__ __launch_bounds__(256)
void nerf_comp(const float* __restrict__ zv,
               const float* __restrict__ o_sigma, const float* __restrict__ o_r,
               const float* __restrict__ o_g, const float* __restrict__ o_b,
               const float* __restrict__ o_bw, float* __restrict__ out)
{
    const int ray  = blockIdx.x * 4 + (threadIdx.x >> 6);
    const int lane = threadIdx.x & 63;
    const int base = ray * SAMP;
    const int s0 = 2 * lane, s1 = s0 + 1;

    const float z0 = zv[base + s0];
    const float z1 = zv[base + s1];
    const float z2 = (lane < 63) ? zv[base + s1 + 1] : 0.0f;
    const float d0 = z1 - z0;
    const float d1 = (lane < 63) ? (z2 - z1) : 1e10f;

    const float sg0 = o_sigma[base + s0], sg1 = o_sigma[base + s1];
    const float a0 = 1.0f - expf(-sg0 * d0);
    const float a1 = 1.0f - expf(-sg1 * d1);
    const float f0 = 1.0f - a0 + 1e-10f;
    const float f1 = 1.0f - a1 + 1e-10f;

    float incl = f0 * f1;
#pragma unroll
    for (int dlt = 1; dlt < 64; dlt <<= 1) {
        const float t = __shfl_up(incl, dlt);
        if (lane >= dlt) incl *= t;
    }
    float ex = __shfl_up(incl, 1);
    if (lane == 0) ex = 1.0f;

    const float t0 = ex;
    const float t1 = ex * f0;
    const float w0 = a0 * t0, w1 = a1 * t1;

    const float bw0 = o_bw[base + s0], bw1 = o_bw[base + s1];
    out[OUT_W  + base + s0] = w0;               out[OUT_W  + base + s1] = w1;
    out[OUT_SW + base + s0] = (1.f - bw0) * w0; out[OUT_SW + base + s1] = (1.f - bw1) * w1;
    out[OUT_DW + base + s0] = bw0 * w0;         out[OUT_DW + base + s1] = bw1 * w1;

    float pr = w0 * o_r[base + s0] + w1 * o_r[base + s1];
    float pg = w0 * o_g[base + s0] + w1 * o_g[base + s1];
    float pb = w0 * o_b[base + s0] + w1 * o_b[base + s1];
    float pd = w0 * z0 + w1 * z1;
#pragma unroll
    for (int dlt = 32; dlt >= 1; dlt >>= 1) {
        pr += __shfl_down(pr, dlt);
        pg += __shfl_down(pg, dlt);
        pb += __shfl_down(pb, dlt);
        pd += __shfl_down(pd, dlt);
    }
    if (lane == 0) {
        out[OUT_RGB + ray * 3 + 0] = pr;
        out[OUT_RGB + ray * 3 + 1] = pg;
        out[OUT_RGB + ray * 3 + 2] = pb;
        out[OUT_DEPTH + ray] = pd;
    }
}

extern "C" void kernel_launch(void* const* d_in, const int* in_sizes, int n_in,
                              void* d_out, int out_size, void* d_ws, size_t ws_size,
                              hipStream_t stream)
{
    const float* points = (const float*)d_in[0];
    const float* dirsv  = (const float*)d_in[1];
    const float* zvals  = (const float*)d_in[2];
    const float* timev  = (const float*)d_in[3];

    const float *sW[5], *sb[5], *dW[5], *db[5];
    if (in_sizes[6] == 99 * 256) {
        for (int i = 0; i < 5; i++) {   // interleaved (sW_i, sb_i, dW_i, db_i)
            sW[i] = (const float*)d_in[4 + 4 * i + 0];
            sb[i] = (const float*)d_in[4 + 4 * i + 1];
            dW[i] = (const float*)d_in[4 + 4 * i + 2];
            db[i] = (const float*)d_in[4 + 4 * i + 3];
        }
    } else {
        for (int i = 0; i < 5; i++) {   // all static then all dynamic
            sW[i] = (const float*)d_in[4 + 2 * i + 0];
            sb[i] = (const float*)d_in[4 + 2 * i + 1];
            dW[i] = (const float*)d_in[14 + 2 * i + 0];
            db[i] = (const float*)d_in[14 + 2 * i + 1];
        }
    }

    // ws layout: bf16 weights (933888 B) then 5 fp32 per-sample arrays (1 MB each)
    short* wt = (short*)d_ws;
    float* ws = (float*)((char*)d_ws + (size_t)WTOT * 2);
    float* o_sigma = ws;
    float* o_r  = ws + (size_t)MTOT * 1;
    float* o_g  = ws + (size_t)MTOT * 2;
    float* o_b  = ws + (size_t)MTOT * 3;
    float* o_bw = ws + (size_t)MTOT * 4;

    prep_weights<<<34, 256, 0, stream>>>(
        sW[0], sW[1], sW[2], sW[3], sW[4], dW[0], dW[1], dW[2], dW[3], dW[4], wt);

    nerf_mlp<<<MTOT / BM, 256, 0, stream>>>(points, dirsv, timev, wt,
        sb[0], sb[1], sb[2], sb[3], sb[4], db[0], db[1], db[2], db[3], db[4],
        o_sigma, o_r, o_g, o_b, o_bw);

    nerf_comp<<<RAYS / 4, 256, 0, stream>>>(zvals, o_sigma, o_r, o_g, o_b, o_bw,
                                            (float*)d_out);
}

// Round 10
// 615.378 us; speedup vs baseline: 1.0336x; 1.0180x over previous
//
#include <hip/hip_runtime.h>
#include <math.h>

// FusionNeRF round 12:
//   - r11 post-mortem: mlp 555->547 (bar-skip + setprio held). But prep rewrite
//     REGRESSED the total (gap 59->78us): 34 blocks = 13% machine occupancy,
//     latency-bound. Fix: 2-D (64k x 64n) tile split -> 120 blocks, T[64][66]
//     (8.4KB), coalesced both sides, 16-iter loops. Bit-identical wt output.
//   - comp: float2 loads/stores (arrays consumed at s0=2*lane stride-2 ->
//     lane-pair float2 is fully coalesced); z2 via __shfl_down, not a 3rd load.
//   - mlp untouched (proven 547us shape: r8 protocol + BAR1-skip + setprio).

#define RAYS 2048
#define SAMP 128
#define MTOT (RAYS * SAMP)
#define HD   256
#define BM   64              // samples per block
#define ES   136             // enc LDS stride (bf16), Kpad=128 (+8 pad, 272B rows)
#define HS   264             // hidden LDS stride (bf16), 256 (+8 pad, 528B rows)

// output float offsets
#define OUT_RGB   0
#define OUT_DEPTH 6144
#define OUT_W     8192
#define OUT_SW    270336
#define OUT_DW    532480

// bf16 weight workspace offsets (elements)
#define SW0 0
#define SW1 32768
#define SW2 98304
#define SW3 163840
#define SW4 229376
#define DW0 233472
#define DW1 266240
#define DW2 331776
#define DW3 397312
#define DW4 462848
#define WTOT 466944

typedef __attribute__((ext_vector_type(8))) short short8;
typedef __attribute__((ext_vector_type(4))) float f32x4;
typedef __attribute__((ext_vector_type(2))) unsigned int uint2v;

__device__ __forceinline__ float sigm(float x) { return 1.0f / (1.0f + expf(-x)); }

__device__ __forceinline__ short f2bf(float f) {   // RNE fp32 -> bf16
    union { float f; unsigned u; } v; v.f = f;
    unsigned r = v.u + 0x7fffu + ((v.u >> 16) & 1u);
    return (short)(r >> 16);
}

// Unmovable memory ops (volatile asm). Counted waits + sched_barrier(0) (rule #18).
#define GLB_LOAD(dst, ptr, imm) \
    asm volatile("global_load_dwordx4 %0, %1, off offset:%c2" \
                 : "=v"(dst) : "v"(ptr), "n"(imm))
#define LDS_READ(dst, addr, imm) \
    asm volatile("ds_read_b128 %0, %1 offset:%c2" \
                 : "=v"(dst) : "v"(addr), "n"(imm))
#define WAITCNT(vm, lg) do { \
    asm volatile("s_waitcnt vmcnt(%c0) lgkmcnt(%c1)" :: "n"(vm), "n"(lg)); \
    __builtin_amdgcn_sched_barrier(0); } while (0)

// Barrier with LDS drain only (validated r5/r8).
__device__ __forceinline__ void bar_lgkm() {
    __builtin_amdgcn_sched_barrier(0);
    asm volatile("s_waitcnt lgkmcnt(0)\n\ts_barrier" ::: "memory");
    __builtin_amdgcn_sched_barrier(0);
}
// Ordering-only barrier (all reads already drained via counted waits).
__device__ __forceinline__ void bar_only() {
    __builtin_amdgcn_sched_barrier(0);
    asm volatile("s_barrier" ::: "memory");
    __builtin_amdgcn_sched_barrier(0);
}

// ---------------- weight prep: 2-D tiled LDS-transpose, 120 blocks --------------
// Block = one (64k x 64n) tile of one matrix. Read coalesced over n (256B/wave),
// write coalesced over k (128B/wave). Tail mats (N=4/5) use one 16-row n-tile;
// guarded reads zero-fill the pad, matching the old layout bit-exactly.
__global__ __launch_bounds__(256)
void prep_weights(const float* sW0, const float* sW1, const float* sW2,
                  const float* sW3, const float* sW4,
                  const float* dW0, const float* dW1, const float* dW2,
                  const float* dW3, const float* dW4, short* __restrict__ dst)
{
    const int b = blockIdx.x, tid = threadIdx.x;
    const float* src; int K, N, Kpad, Nr; size_t doff; int loc;
    if      (b <   8) { src = sW0; K =  90; N = 256; Kpad = 128; doff = SW0; Nr = 64; loc = b;       }
    else if (b <  24) { src = sW1; K = 256; N = 256; Kpad = 256; doff = SW1; Nr = 64; loc = b - 8;   }
    else if (b <  40) { src = sW2; K = 256; N = 256; Kpad = 256; doff = SW2; Nr = 64; loc = b - 24;  }
    else if (b <  56) { src = sW3; K = 256; N = 256; Kpad = 256; doff = SW3; Nr = 64; loc = b - 40;  }
    else if (b <  60) { src = sW4; K = 256; N =   4; Kpad = 256; doff = SW4; Nr = 16; loc = b - 56;  }
    else if (b <  68) { src = dW0; K =  99; N = 256; Kpad = 128; doff = DW0; Nr = 64; loc = b - 60;  }
    else if (b <  84) { src = dW1; K = 256; N = 256; Kpad = 256; doff = DW1; Nr = 64; loc = b - 68;  }
    else if (b < 100) { src = dW2; K = 256; N = 256; Kpad = 256; doff = DW2; Nr = 64; loc = b - 84;  }
    else if (b < 116) { src = dW3; K = 256; N = 256; Kpad = 256; doff = DW3; Nr = 64; loc = b - 100; }
    else              { src = dW4; K = 256; N =   5; Kpad = 256; doff = DW4; Nr = 16; loc = b - 116; }

    const int kt = Kpad >> 6;              // k-tiles per matrix
    const int k0 = (loc % kt) * 64, n0 = (loc / kt) * 64;

    __shared__ short T[64][66];            // 8448 B; 33-dword rows -> conflict-free

    for (int idx = tid; idx < 64 * 64; idx += 256) {     // read: coalesced over nn
        const int k = idx >> 6, nn = idx & 63;
        const float v = (k0 + k < K && n0 + nn < N) ? src[(k0 + k) * N + n0 + nn] : 0.0f;
        T[nn][k] = f2bf(v);
    }
    __syncthreads();

    for (int idx = tid; idx < Nr * 64; idx += 256) {     // write: coalesced over k
        const int n = idx >> 6, k = idx & 63;
        dst[doff + (size_t)(n0 + n) * Kpad + k0 + k] = T[n][k];
    }
}

// ---------------- MFMA dense layer: self-contained asm k-pipeline (r8/r11) ------
// A-operand = weights Wt[256][K] (global, L2-hot), B-operand = acts [64][AS] (LDS).
// Entry: issue k0+k1 weights (GLB) + k0+k1 acts (LDS), wait (4,4).
// Steady: issue kk+1 (4 GLB + 4 LDS), wait (4,4). Last: wait (0,0) — layer
// self-contained; nothing in flight crosses plain-C code.
// BAR1: emit the pre-epilogue alias barrier (false when A and O don't alias).
template <int KSTEPS, bool RELU, int AS, bool BAR1 = true>
__device__ __forceinline__ void layer256(const short* A,
                                         const short* __restrict__ Wt,
                                         const float* __restrict__ bias,
                                         short* O, int Os, int tid)
{
    const int w = tid >> 6, lane = tid & 63, qq = lane >> 4, col = lane & 15;
    constexpr int K = KSTEPS * 32;

    const short* wp0 = Wt + (size_t)(w * 64 +  0 + col) * K + qq * 8;
    const short* wp1 = Wt + (size_t)(w * 64 + 16 + col) * K + qq * 8;
    const short* wp2 = Wt + (size_t)(w * 64 + 32 + col) * K + qq * 8;
    const short* wp3 = Wt + (size_t)(w * 64 + 48 + col) * K + qq * 8;
    // LDS byte address (generic shared addr: low 32 bits are the LDS offset)
    const unsigned ab = (unsigned)(size_t)(const void*)A + (unsigned)((col * AS + qq * 8) * 2);

    short8 wa[2][4], ba[2][4];   // ping-pong, all indices compile-time after unroll

    GLB_LOAD(wa[0][0], wp0, 0);
    GLB_LOAD(wa[0][1], wp1, 0);
    GLB_LOAD(wa[0][2], wp2, 0);
    GLB_LOAD(wa[0][3], wp3, 0);
    GLB_LOAD(wa[1][0], wp0, 64);
    GLB_LOAD(wa[1][1], wp1, 64);
    GLB_LOAD(wa[1][2], wp2, 64);
    GLB_LOAD(wa[1][3], wp3, 64);
    LDS_READ(ba[0][0], ab, (0 * 16 * AS) * 2);
    LDS_READ(ba[0][1], ab, (1 * 16 * AS) * 2);
    LDS_READ(ba[0][2], ab, (2 * 16 * AS) * 2);
    LDS_READ(ba[0][3], ab, (3 * 16 * AS) * 2);
    LDS_READ(ba[1][0], ab, (0 * 16 * AS) * 2 + 64);
    LDS_READ(ba[1][1], ab, (1 * 16 * AS) * 2 + 64);
    LDS_READ(ba[1][2], ab, (2 * 16 * AS) * 2 + 64);
    LDS_READ(ba[1][3], ab, (3 * 16 * AS) * 2 + 64);
    WAITCNT(4, 4);   // k0 weights+acts ready; k1 in flight

    f32x4 acc[4][4];
#pragma unroll
    for (int ft = 0; ft < 4; ft++)
#pragma unroll
        for (int st = 0; st < 4; st++) acc[ft][st] = (f32x4)0.0f;

#pragma unroll
    for (int kk = 0; kk < KSTEPS; kk++) {
        const int c = kk & 1, nx = c ^ 1;
        if (kk > 0 && kk < KSTEPS - 1) {
            GLB_LOAD(wa[nx][0], wp0, (kk + 1) * 64);
            GLB_LOAD(wa[nx][1], wp1, (kk + 1) * 64);
            GLB_LOAD(wa[nx][2], wp2, (kk + 1) * 64);
            GLB_LOAD(wa[nx][3], wp3, (kk + 1) * 64);
            LDS_READ(ba[nx][0], ab, (0 * 16 * AS) * 2 + (kk + 1) * 64);
            LDS_READ(ba[nx][1], ab, (1 * 16 * AS) * 2 + (kk + 1) * 64);
            LDS_READ(ba[nx][2], ab, (2 * 16 * AS) * 2 + (kk + 1) * 64);
            LDS_READ(ba[nx][3], ab, (3 * 16 * AS) * 2 + (kk + 1) * 64);
            WAITCNT(4, 4);                 // wa[kk]/ba[kk] ready; kk+1 in flight
        } else if (kk == KSTEPS - 1) {
            WAITCNT(0, 0);                 // drain: layer self-contained
        }
        __builtin_amdgcn_s_setprio(1);     // T5: favor MFMA cluster vs phase-diverse siblings
#pragma unroll
        for (int ft = 0; ft < 4; ft++)
#pragma unroll
            for (int st = 0; st < 4; st++)
                acc[ft][st] = __builtin_amdgcn_mfma_f32_16x16x32_bf16(
                    wa[c][ft], ba[c][st], acc[ft][st], 0, 0, 0);
        __builtin_amdgcn_s_setprio(0);
    }

    if (BAR1) bar_only();   // waves done reading A (needed only when A aliases O)

#pragma unroll
    for (int ft = 0; ft < 4; ft++) {
        const f32x4 bv = *(const f32x4*)(bias + w * 64 + ft * 16 + qq * 4);
#pragma unroll
        for (int st = 0; st < 4; st++) {
            float v0 = acc[ft][st][0] + bv[0];
            float v1 = acc[ft][st][1] + bv[1];
            float v2 = acc[ft][st][2] + bv[2];
            float v3 = acc[ft][st][3] + bv[3];
            if (RELU) {
                v0 = fmaxf(v0, 0.0f); v1 = fmaxf(v1, 0.0f);
                v2 = fmaxf(v2, 0.0f); v3 = fmaxf(v3, 0.0f);
            }
            unsigned p0, p1;   // RNE pack, matches f2bf
            asm("v_cvt_pk_bf16_f32 %0, %1, %2" : "=v"(p0) : "v"(v0), "v"(v1));
            asm("v_cvt_pk_bf16_f32 %0, %1, %2" : "=v"(p1) : "v"(v2), "v"(v3));
            uint2v pk; pk[0] = p0; pk[1] = p1;
            *(uint2v*)(O + (size_t)(st * 16 + col) * Os + w * 64 + ft * 16 + qq * 4) = pk;
        }
    }
    bar_lgkm();   // O visible to next layer
}

// head (swapped): A-op = head weights Wt[16][256], B-op = acts of wave's 16 samples.
// Plain C — our asm queues are empty here (layers drain), compiler accounting exact.
template <int NV, int OS>
__device__ __forceinline__ void head256(const short* A, int As,
                                        const short* __restrict__ Wt,
                                        const float* __restrict__ bias,
                                        float* Out, int tid)
{
    const int w = tid >> 6, lane = tid & 63, qq = lane >> 4, col = lane & 15;
    f32x4 acc = (f32x4)0.0f;
#pragma unroll
    for (int kk = 0; kk < 8; kk++) {
        short8 a = *(const short8*)(Wt + col * 256 + kk * 32 + qq * 8);
        short8 b = *(const short8*)(A + (size_t)(w * 16 + col) * As + kk * 32 + qq * 8);
        acc = __builtin_amdgcn_mfma_f32_16x16x32_bf16(a, b, acc, 0, 0, 0);
    }
    const int s = w * 16 + col;
    if (qq == 0) {
#pragma unroll
        for (int i = 0; i < 4; i++) Out[s * OS + i] = acc[i] + bias[i];
    } else if (NV == 5 && qq == 1) {
        Out[s * OS + 4] = acc[0] + bias[4];
    }
}

__global__ __launch_bounds__(256, 3)
void nerf_mlp(const float* __restrict__ points, const float* __restrict__ dirsv,
              const float* __restrict__ timev, const short* __restrict__ wt,
              const float* __restrict__ sb0, const float* __restrict__ sb1,
              const float* __restrict__ sb2, const float* __restrict__ sb3,
              const float* __restrict__ sb4,
              const float* __restrict__ db0, const float* __restrict__ db1,
              const float* __restrict__ db2, const float* __restrict__ db3,
              const float* __restrict__ db4,
              float* __restrict__ o_sigma, float* __restrict__ o_r,
              float* __restrict__ o_g, float* __restrict__ o_b,
              float* __restrict__ o_bw)
{
    __shared__ __align__(16) short E[BM][ES];   // 17408 B
    __shared__ __align__(16) short Hb[BM][HS];  // 33792 B
    __shared__ float so[BM][4];                 //  1024 B
    __shared__ float dn[BM][5];                 //  1280 B -> 53504 B => 3 blocks/CU

    const int tid = threadIdx.x;
    const int m0  = blockIdx.x * BM;

    // ---- positional encoding -> E (bf16). sinf/cosf (no sincosf scratch). ----
    for (int idx = tid; idx < BM * 64; idx += 256) {
        const int s = idx >> 6, j = idx & 63, m = m0 + s;
        if (j < 46) {
            float x; int dsin, dcos;
            if (j < 30) {                       // pos: 10 bands x 3 coords
                const int l = j / 3, c = j - 3 * l;
                x = points[m * 3 + c] * (float)(1 << l);
                dsin = 3 + l * 6 + c; dcos = dsin + 3;
            } else if (j < 42) {                // dirs: 4 bands x 3 coords
                const int jj = j - 30, l = jj / 3, c = jj - 3 * l;
                x = dirsv[m * 3 + c] * (float)(1 << l);
                dsin = 66 + l * 6 + c; dcos = dsin + 3;
            } else {                            // time: 4 bands x 1
                const int l = j - 42;
                x = timev[m] * (float)(1 << l);
                dsin = 91 + 2 * l; dcos = dsin + 1;
            }
            E[s][dsin] = f2bf(sinf(x));
            E[s][dcos] = f2bf(cosf(x));
        } else {                                // passthroughs + zero pad
            int t = (j - 46) * 2;
#pragma unroll
            for (int u = 0; u < 2; u++, t++) {
                float v = 0.0f; int d;
                if (t < 3)       { d = t;        v = points[m * 3 + t]; }
                else if (t < 6)  { d = 60 + t;   v = dirsv[m * 3 + t - 3]; }  // 63..65
                else if (t == 6) { d = 90;       v = timev[m]; }
                else             { d = 92 + t; }                              // 99..127 = 0
                E[s][d] = f2bf(v);
            }
        }
    }
    bar_lgkm();

    // ---- static MLP ----
    layer256<4, true, ES, false>(&E[0][0],  wt + SW0, sb0, &Hb[0][0], HS, tid);  // E->Hb: no alias
    layer256<8, true, HS>(&Hb[0][0], wt + SW1, sb1, &Hb[0][0], HS, tid);
    layer256<8, true, HS>(&Hb[0][0], wt + SW2, sb2, &Hb[0][0], HS, tid);
    layer256<8, true, HS>(&Hb[0][0], wt + SW3, sb3, &Hb[0][0], HS, tid);
    head256<4, 4>(&Hb[0][0], HS, wt + SW4, sb4, &so[0][0], tid);
    // (dynamic L0's bar_only orders these head reads of Hb vs its Hb overwrite)

    // ---- dynamic MLP ----
    layer256<4, true, ES>(&E[0][0],  wt + DW0, db0, &Hb[0][0], HS, tid);  // keeps BAR1
    layer256<8, true, HS>(&Hb[0][0], wt + DW1, db1, &Hb[0][0], HS, tid);
    layer256<8, true, HS>(&Hb[0][0], wt + DW2, db2, &Hb[0][0], HS, tid);
    layer256<8, true, HS>(&Hb[0][0], wt + DW3, db3, &Hb[0][0], HS, tid);
    head256<5, 5>(&Hb[0][0], HS, wt + DW4, db4, &dn[0][0], tid);
    bar_lgkm();

    // ---- blend ----
    if (tid < BM) {
        const int s = tid, m = m0 + s;
        const float bw = sigm(dn[s][4]);
        const float sigma = (1.f - bw) * so[s][0] + bw * dn[s][0];
        const float r  = (1.f - bw) * sigm(so[s][1]) + bw * sigm(dn[s][1]);
        const float gg = (1.f - bw) * sigm(so[s][2]) + bw * sigm(dn[s][2]);
        const float bb = (1.f - bw) * sigm(so[s][3]) + bw * sigm(dn[s][3]);
        o_sigma[m] = sigma; o_r[m] = r; o_g[m] = gg; o_b[m] = bb; o_bw[m] = bw;
    }
}

// ---------------- compositing: one wave per ray, float2-vectorized --------------
typedef __attribute__((ext_vector_type(2))) float f32x2;

__global__ __launch_bounds__(256)
void nerf_comp(const float* __restrict__ zv,
               const float* __restrict__ o_sigma, const float* __restrict__ o_r,
               const float* __restrict__ o_g, const float* __restrict__ o_b,
               const float* __restrict__ o_bw, float* __restrict__ out)
{
    const int ray  = blockIdx.x * 4 + (threadIdx.x >> 6);
    const int lane = threadIdx.x & 63;
    const int base = ray * SAMP;

    const f32x2 z01 = *(const f32x2*)(zv + base + 2 * lane);
    const float z0 = z01[0], z1 = z01[1];
    const float z2 = __shfl_down(z0, 1);          // next pair's z0 (lane 63 guarded)
    const float d0 = z1 - z0;
    const float d1 = (lane < 63) ? (z2 - z1) : 1e10f;

    const f32x2 sg = *(const f32x2*)(o_sigma + base + 2 * lane);
    const float a0 = 1.0f - expf(-sg[0] * d0);
    const float a1 = 1.0f - expf(-sg[1] * d1);
    const float f0 = 1.0f - a0 + 1e-10f;
    const float f1 = 1.0f - a1 + 1e-10f;

    // inclusive multiplicative scan of p = f0*f1 across lanes
    float incl = f0 * f1;
#pragma unroll
    for (int dlt = 1; dlt < 64; dlt <<= 1) {
        const float t = __shfl_up(incl, dlt);
        if (lane >= dlt) incl *= t;
    }
    float ex = __shfl_up(incl, 1);
    if (lane == 0) ex = 1.0f;

    const float t0 = ex;
    const float t1 = ex * f0;
    const float w0 = a0 * t0, w1 = a1 * t1;

    const f32x2 bw2 = *(const f32x2*)(o_bw + base + 2 * lane);
    f32x2 vw;  vw[0] = w0;                 vw[1] = w1;
    f32x2 vsw; vsw[0] = (1.f - bw2[0]) * w0; vsw[1] = (1.f - bw2[1]) * w1;
    f32x2 vdw; vdw[0] = bw2[0] * w0;       vdw[1] = bw2[1] * w1;
    *(f32x2*)(out + OUT_W  + base + 2 * lane) = vw;
    *(f32x2*)(out + OUT_SW + base + 2 * lane) = vsw;
    *(f32x2*)(out + OUT_DW + base + 2 * lane) = vdw;

    const f32x2 r2 = *(const f32x2*)(o_r + base + 2 * lane);
    const f32x2 g2 = *(const f32x2*)(o_g + base + 2 * lane);
    const f32x2 b2 = *(const f32x2*)(o_b + base + 2 * lane);
    float pr = w0 * r2[0] + w1 * r2[1];
    float pg = w0 * g2[0] + w1 * g2[1];
    float pb = w0 * b2[0] + w1 * b2[1];
    float pd = w0 * z0 + w1 * z1;
#pragma unroll
    for (int dlt = 32; dlt >= 1; dlt >>= 1) {
        pr += __shfl_down(pr, dlt);
        pg += __shfl_down(pg, dlt);
        pb += __shfl_down(pb, dlt);
        pd += __shfl_down(pd, dlt);
    }
    if (lane == 0) {
        out[OUT_RGB + ray * 3 + 0] = pr;
        out[OUT_RGB + ray * 3 + 1] = pg;
        out[OUT_RGB + ray * 3 + 2] = pb;
        out[OUT_DEPTH + ray] = pd;
    }
}

extern "C" void kernel_launch(void* const* d_in, const int* in_sizes, int n_in,
                              void* d_out, int out_size, void* d_ws, size_t ws_size,
                              hipStream_t stream)
{
    const float* points = (const float*)d_in[0];
    const float* dirsv  = (const float*)d_in[1];
    const float* zvals  = (const float*)d_in[2];
    const float* timev  = (const float*)d_in[3];

    const float *sW[5], *sb[5], *dW[5], *db[5];
    if (in_sizes[6] == 99 * 256) {
        for (int i = 0; i < 5; i++) {   // interleaved (sW_i, sb_i, dW_i, db_i)
            sW[i] = (const float*)d_in[4 + 4 * i + 0];
            sb[i] = (const float*)d_in[4 + 4 * i + 1];
            dW[i] = (const float*)d_in[4 + 4 * i + 2];
            db[i] = (const float*)d_in[4 + 4 * i + 3];
        }
    } else {
        for (int i = 0; i < 5; i++) {   // all static then all dynamic
            sW[i] = (const float*)d_in[4 + 2 * i + 0];
            sb[i] = (const float*)d_in[4 + 2 * i + 1];
            dW[i] = (const float*)d_in[14 + 2 * i + 0];
            db[i] = (const float*)d_in[14 + 2 * i + 1];
        }
    }

    // ws layout: bf16 weights (933888 B) then 5 fp32 per-sample arrays (1 MB each)
    short* wt = (short*)d_ws;
    float* ws = (float*)((char*)d_ws + (size_t)WTOT * 2);
    float* o_sigma = ws;
    float* o_r  = ws + (size_t)MTOT * 1;
    float* o_g  = ws + (size_t)MTOT * 2;
    float* o_b  = ws + (size_t)MTOT * 3;
    float* o_bw = ws + (size_t)MTOT * 4;

    prep_weights<<<120, 256, 0, stream>>>(
        sW[0], sW[1], sW[2], sW[3], sW[4], dW[0], dW[1], dW[2], dW[3], dW[4], wt);

    nerf_mlp<<<MTOT / BM, 256, 0, stream>>>(points, dirsv, timev, wt,
        sb[0], sb[1], sb[2], sb[3], sb[4], db[0], db[1], db[2], db[3], db[4],
        o_sigma, o_r, o_g, o_b, o_bw);

    nerf_comp<<<RAYS / 4, 256, 0, stream>>>(zvals, o_sigma, o_r, o_g, o_b, o_bw,
                                            (float*)d_out);
}

// Round 12
// 563.547 us; speedup vs baseline: 1.1287x; 1.0920x over previous
//
#include <hip/hip_runtime.h>
#include <math.h>

// FusionNeRF round 14 (consolidation):
//   - r13 never ran (infra). Re-audit found a real race in the cross-layer
//     carry: regalloc copies of carried in-flight asm-load dests before the
//     consuming layer's waitcnt read un-retired registers (r7's failure class,
//     wider window). Carry DROPPED (expected win was only ~2.4% anyway).
//   - Gap ledger (total - mlp): original 1824-block prep = 59us; 34-block = 79;
//     120-block = 70. Weights are L2-resident (1.8MB) so the strided original
//     wins on occupancy -> REVERT prep to the original.
//   - Kept: r12 mlp shape (545us: r8 counted-wait protocol + BAR1-skip +
//     setprio), float2 comp.
//   - NEW: double-angle trig encoding (one sinf/cosf per (sample,channel),
//     sin2t=2sc / cos2t=c^2-s^2 per band; 2944 -> 448 ocml calls/block).
//     Recurrence err ~5e-5 << bf16 quantum. Wave-uniform branches.

#define RAYS 2048
#define SAMP 128
#define MTOT (RAYS * SAMP)
#define HD   256
#define BM   64              // samples per block
#define ES   136             // enc LDS stride (bf16), Kpad=128 (+8 pad, 272B rows)
#define HS   264             // hidden LDS stride (bf16), 256 (+8 pad, 528B rows)

// output float offsets
#define OUT_RGB   0
#define OUT_DEPTH 6144
#define OUT_W     8192
#define OUT_SW    270336
#define OUT_DW    532480

// bf16 weight workspace offsets (elements)
#define SW0 0
#define SW1 32768
#define SW2 98304
#define SW3 163840
#define SW4 229376
#define DW0 233472
#define DW1 266240
#define DW2 331776
#define DW3 397312
#define DW4 462848
#define WTOT 466944

typedef __attribute__((ext_vector_type(8))) short short8;
typedef __attribute__((ext_vector_type(4))) float f32x4;
typedef __attribute__((ext_vector_type(2))) float f32x2;
typedef __attribute__((ext_vector_type(2))) unsigned int uint2v;

__device__ __forceinline__ float sigm(float x) { return 1.0f / (1.0f + expf(-x)); }

__device__ __forceinline__ short f2bf(float f) {   // RNE fp32 -> bf16
    union { float f; unsigned u; } v; v.f = f;
    unsigned r = v.u + 0x7fffu + ((v.u >> 16) & 1u);
    return (short)(r >> 16);
}

// Unmovable memory ops (volatile asm). Counted waits + sched_barrier(0) (rule #18).
#define GLB_LOAD(dst, ptr, imm) \
    asm volatile("global_load_dwordx4 %0, %1, off offset:%c2" \
                 : "=v"(dst) : "v"(ptr), "n"(imm))
#define LDS_READ(dst, addr, imm) \
    asm volatile("ds_read_b128 %0, %1 offset:%c2" \
                 : "=v"(dst) : "v"(addr), "n"(imm))
#define WAITCNT(vm, lg) do { \
    asm volatile("s_waitcnt vmcnt(%c0) lgkmcnt(%c1)" :: "n"(vm), "n"(lg)); \
    __builtin_amdgcn_sched_barrier(0); } while (0)

// Barrier with LDS drain only (validated r5/r8/r11/r12).
__device__ __forceinline__ void bar_lgkm() {
    __builtin_amdgcn_sched_barrier(0);
    asm volatile("s_waitcnt lgkmcnt(0)\n\ts_barrier" ::: "memory");
    __builtin_amdgcn_sched_barrier(0);
}
// Ordering-only barrier (all reads already drained via counted waits).
__device__ __forceinline__ void bar_only() {
    __builtin_amdgcn_sched_barrier(0);
    asm volatile("s_barrier" ::: "memory");
    __builtin_amdgcn_sched_barrier(0);
}

// ---------------- weight prep: W[K][N] fp32 -> Wt[Npad][Kpad] bf16 --------------
// Original 1824-block version: strided reads are L2-absorbed (weights 1.8MB);
// high block count beats coalescing here (gap ledger: 59us vs 70/79us rewrites).
__device__ __forceinline__ void conv1(const float* __restrict__ src, short* __restrict__ dst,
                                      int local, int K, int N, int Kpad) {
    const int n = local / Kpad, k = local - n * Kpad;
    const float v = (k < K && n < N) ? src[k * N + n] : 0.0f;
    dst[local] = f2bf(v);
}

__global__ __launch_bounds__(256)
void prep_weights(const float* sW0, const float* sW1, const float* sW2,
                  const float* sW3, const float* sW4,
                  const float* dW0, const float* dW1, const float* dW2,
                  const float* dW3, const float* dW4, short* __restrict__ dst)
{
    const int idx = blockIdx.x * 256 + threadIdx.x;
    if (idx >= WTOT) return;
    if      (idx < SW1) conv1(sW0, dst + SW0, idx - SW0,  90, 256, 128);
    else if (idx < SW2) conv1(sW1, dst + SW1, idx - SW1, 256, 256, 256);
    else if (idx < SW3) conv1(sW2, dst + SW2, idx - SW2, 256, 256, 256);
    else if (idx < SW4) conv1(sW3, dst + SW3, idx - SW3, 256, 256, 256);
    else if (idx < DW0) conv1(sW4, dst + SW4, idx - SW4, 256,   4, 256);
    else if (idx < DW1) conv1(dW0, dst + DW0, idx - DW0,  99, 256, 128);
    else if (idx < DW2) conv1(dW1, dst + DW1, idx - DW1, 256, 256, 256);
    else if (idx < DW3) conv1(dW2, dst + DW2, idx - DW2, 256, 256, 256);
    else if (idx < DW4) conv1(dW3, dst + DW3, idx - DW3, 256, 256, 256);
    else                conv1(dW4, dst + DW4, idx - DW4, 256,   5, 256);
}

// ---------------- MFMA dense layer: self-contained asm k-pipeline (r12) ---------
// A-operand = weights Wt[256][K] (global, L2-hot), B-operand = acts [64][AS] (LDS).
// Entry: issue k0+k1 weights (GLB) + k0+k1 acts (LDS), wait (4,4).
// Steady: issue kk+1 (4 GLB + 4 LDS), wait (4,4). Last: wait (0,0) — layer
// self-contained; nothing in flight crosses plain-C code.
// BAR1: emit the pre-epilogue alias barrier (false when A and O don't alias).
template <int KSTEPS, bool RELU, int AS, bool BAR1 = true>
__device__ __forceinline__ void layer256(const short* A,
                                         const short* __restrict__ Wt,
                                         const float* __restrict__ bias,
                                         short* O, int Os, int tid)
{
    const int w = tid >> 6, lane = tid & 63, qq = lane >> 4, col = lane & 15;
    constexpr int K = KSTEPS * 32;

    const short* wp0 = Wt + (size_t)(w * 64 +  0 + col) * K + qq * 8;
    const short* wp1 = Wt + (size_t)(w * 64 + 16 + col) * K + qq * 8;
    const short* wp2 = Wt + (size_t)(w * 64 + 32 + col) * K + qq * 8;
    const short* wp3 = Wt + (size_t)(w * 64 + 48 + col) * K + qq * 8;
    // LDS byte address (generic shared addr: low 32 bits are the LDS offset)
    const unsigned ab = (unsigned)(size_t)(const void*)A + (unsigned)((col * AS + qq * 8) * 2);

    short8 wa[2][4], ba[2][4];   // ping-pong, all indices compile-time after unroll

    GLB_LOAD(wa[0][0], wp0, 0);
    GLB_LOAD(wa[0][1], wp1, 0);
    GLB_LOAD(wa[0][2], wp2, 0);
    GLB_LOAD(wa[0][3], wp3, 0);
    GLB_LOAD(wa[1][0], wp0, 64);
    GLB_LOAD(wa[1][1], wp1, 64);
    GLB_LOAD(wa[1][2], wp2, 64);
    GLB_LOAD(wa[1][3], wp3, 64);
    LDS_READ(ba[0][0], ab, (0 * 16 * AS) * 2);
    LDS_READ(ba[0][1], ab, (1 * 16 * AS) * 2);
    LDS_READ(ba[0][2], ab, (2 * 16 * AS) * 2);
    LDS_READ(ba[0][3], ab, (3 * 16 * AS) * 2);
    LDS_READ(ba[1][0], ab, (0 * 16 * AS) * 2 + 64);
    LDS_READ(ba[1][1], ab, (1 * 16 * AS) * 2 + 64);
    LDS_READ(ba[1][2], ab, (2 * 16 * AS) * 2 + 64);
    LDS_READ(ba[1][3], ab, (3 * 16 * AS) * 2 + 64);
    WAITCNT(4, 4);   // k0 weights+acts ready; k1 in flight

    f32x4 acc[4][4];
#pragma unroll
    for (int ft = 0; ft < 4; ft++)
#pragma unroll
        for (int st = 0; st < 4; st++) acc[ft][st] = (f32x4)0.0f;

#pragma unroll
    for (int kk = 0; kk < KSTEPS; kk++) {
        const int c = kk & 1, nx = c ^ 1;
        if (kk > 0 && kk < KSTEPS - 1) {
            GLB_LOAD(wa[nx][0], wp0, (kk + 1) * 64);
            GLB_LOAD(wa[nx][1], wp1, (kk + 1) * 64);
            GLB_LOAD(wa[nx][2], wp2, (kk + 1) * 64);
            GLB_LOAD(wa[nx][3], wp3, (kk + 1) * 64);
            LDS_READ(ba[nx][0], ab, (0 * 16 * AS) * 2 + (kk + 1) * 64);
            LDS_READ(ba[nx][1], ab, (1 * 16 * AS) * 2 + (kk + 1) * 64);
            LDS_READ(ba[nx][2], ab, (2 * 16 * AS) * 2 + (kk + 1) * 64);
            LDS_READ(ba[nx][3], ab, (3 * 16 * AS) * 2 + (kk + 1) * 64);
            WAITCNT(4, 4);                 // wa[kk]/ba[kk] ready; kk+1 in flight
        } else if (kk == KSTEPS - 1) {
            WAITCNT(0, 0);                 // drain: layer self-contained
        }
        __builtin_amdgcn_s_setprio(1);     // T5: favor MFMA cluster vs phase-diverse siblings
#pragma unroll
        for (int ft = 0; ft < 4; ft++)
#pragma unroll
            for (int st = 0; st < 4; st++)
                acc[ft][st] = __builtin_amdgcn_mfma_f32_16x16x32_bf16(
                    wa[c][ft], ba[c][st], acc[ft][st], 0, 0, 0);
        __builtin_amdgcn_s_setprio(0);
    }

    if (BAR1) bar_only();   // waves done reading A (needed only when A aliases O)

#pragma unroll
    for (int ft = 0; ft < 4; ft++) {
        const f32x4 bv = *(const f32x4*)(bias + w * 64 + ft * 16 + qq * 4);
#pragma unroll
        for (int st = 0; st < 4; st++) {
            float v0 = acc[ft][st][0] + bv[0];
            float v1 = acc[ft][st][1] + bv[1];
            float v2 = acc[ft][st][2] + bv[2];
            float v3 = acc[ft][st][3] + bv[3];
            if (RELU) {
                v0 = fmaxf(v0, 0.0f); v1 = fmaxf(v1, 0.0f);
                v2 = fmaxf(v2, 0.0f); v3 = fmaxf(v3, 0.0f);
            }
            unsigned p0, p1;   // RNE pack, matches f2bf
            asm("v_cvt_pk_bf16_f32 %0, %1, %2" : "=v"(p0) : "v"(v0), "v"(v1));
            asm("v_cvt_pk_bf16_f32 %0, %1, %2" : "=v"(p1) : "v"(v2), "v"(v3));
            uint2v pk; pk[0] = p0; pk[1] = p1;
            *(uint2v*)(O + (size_t)(st * 16 + col) * Os + w * 64 + ft * 16 + qq * 4) = pk;
        }
    }
    bar_lgkm();   // O visible to next layer
}

// head (swapped): A-op = head weights Wt[16][256], B-op = acts of wave's 16 samples.
// Plain C — our asm queues are empty here (layers drain), compiler accounting exact.
template <int NV, int OS>
__device__ __forceinline__ void head256(const short* A, int As,
                                        const short* __restrict__ Wt,
                                        const float* __restrict__ bias,
                                        float* Out, int tid)
{
    const int w = tid >> 6, lane = tid & 63, qq = lane >> 4, col = lane & 15;
    f32x4 acc = (f32x4)0.0f;
#pragma unroll
    for (int kk = 0; kk < 8; kk++) {
        short8 a = *(const short8*)(Wt + col * 256 + kk * 32 + qq * 8);
        short8 b = *(const short8*)(A + (size_t)(w * 16 + col) * As + kk * 32 + qq * 8);
        acc = __builtin_amdgcn_mfma_f32_16x16x32_bf16(a, b, acc, 0, 0, 0);
    }
    const int s = w * 16 + col;
    if (qq == 0) {
#pragma unroll
        for (int i = 0; i < 4; i++) Out[s * OS + i] = acc[i] + bias[i];
    } else if (NV == 5 && qq == 1) {
        Out[s * OS + 4] = acc[0] + bias[4];
    }
}

__global__ __launch_bounds__(256, 3)
void nerf_mlp(const float* __restrict__ points, const float* __restrict__ dirsv,
              const float* __restrict__ timev, const short* __restrict__ wt,
              const float* __restrict__ sb0, const float* __restrict__ sb1,
              const float* __restrict__ sb2, const float* __restrict__ sb3,
              const float* __restrict__ sb4,
              const float* __restrict__ db0, const float* __restrict__ db1,
              const float* __restrict__ db2, const float* __restrict__ db3,
              const float* __restrict__ db4,
              float* __restrict__ o_sigma, float* __restrict__ o_r,
              float* __restrict__ o_g, float* __restrict__ o_b,
              float* __restrict__ o_bw)
{
    __shared__ __align__(16) short E[BM][ES];   // 17408 B
    __shared__ __align__(16) short Hb[BM][HS];  // 33792 B
    __shared__ float so[BM][4];                 //  1024 B
    __shared__ float dn[BM][5];                 //  1280 B -> 53504 B => 3 blocks/CU

    const int tid = threadIdx.x;
    const int m0  = blockIdx.x * BM;

    // ---- positional encoding -> E. Double-angle recurrence: one sinf/cosf per
    //      (sample, channel); sin2t=2sc / cos2t=c^2-s^2 per band. Channels:
    //      0-2 pos (10 bands), 3-5 dirs (4), 6 time (4). c uniform per 64-lane
    //      chunk -> wave-uniform branches. 448 ocml calls/block (was 2944). ----
    for (int idx = tid; idx < 7 * BM; idx += 256) {
        const int c = idx >> 6, s = idx & 63, m = m0 + s;
        float x; int dbase, nb, dstep, coff;
        if (c < 3)      { x = points[m * 3 + c];     E[s][c]      = f2bf(x); dbase = 3 + c;  nb = 10; dstep = 6; coff = 3; }
        else if (c < 6) { x = dirsv[m * 3 + c - 3];  E[s][60 + c] = f2bf(x); dbase = 63 + c; nb = 4;  dstep = 6; coff = 3; }
        else            { x = timev[m];              E[s][90]     = f2bf(x); dbase = 91;     nb = 4;  dstep = 2; coff = 1; }
        float sl = sinf(x), cl = cosf(x);
        int d = dbase;
        E[s][d] = f2bf(sl); E[s][d + coff] = f2bf(cl);
        for (int l = 1; l < nb; l++) {
            const float s2 = 2.0f * sl * cl;
            const float c2 = cl * cl - sl * sl;
            d += dstep;
            E[s][d] = f2bf(s2); E[s][d + coff] = f2bf(c2);
            sl = s2; cl = c2;
        }
    }
    for (int idx = tid; idx < BM * 32; idx += 256) {   // zero pad d=99..127
        const int s = idx >> 5, d = 96 + (idx & 31);
        if (d >= 99) E[s][d] = 0;
    }
    bar_lgkm();

    // ---- static MLP ----
    layer256<4, true, ES, false>(&E[0][0],  wt + SW0, sb0, &Hb[0][0], HS, tid);  // E->Hb: no alias
    layer256<8, true, HS>(&Hb[0][0], wt + SW1, sb1, &Hb[0][0], HS, tid);
    layer256<8, true, HS>(&Hb[0][0], wt + SW2, sb2, &Hb[0][0], HS, tid);
    layer256<8, true, HS>(&Hb[0][0], wt + SW3, sb3, &Hb[0][0], HS, tid);
    head256<4, 4>(&Hb[0][0], HS, wt + SW4, sb4, &so[0][0], tid);
    // (dynamic L0's bar_only orders these head reads of Hb vs its Hb overwrite)

    // ---- dynamic MLP ----
    layer256<4, true, ES>(&E[0][0],  wt + DW0, db0, &Hb[0][0], HS, tid);  // keeps BAR1
    layer256<8, true, HS>(&Hb[0][0], wt + DW1, db1, &Hb[0][0], HS, tid);
    layer256<8, true, HS>(&Hb[0][0], wt + DW2, db2, &Hb[0][0], HS, tid);
    layer256<8, true, HS>(&Hb[0][0], wt + DW3, db3, &Hb[0][0], HS, tid);
    head256<5, 5>(&Hb[0][0], HS, wt + DW4, db4, &dn[0][0], tid);
    bar_lgkm();

    // ---- blend ----
    if (tid < BM) {
        const int s = tid, m = m0 + s;
        const float bw = sigm(dn[s][4]);
        const float sigma = (1.f - bw) * so[s][0] + bw * dn[s][0];
        const float r  = (1.f - bw) * sigm(so[s][1]) + bw * sigm(dn[s][1]);
        const float gg = (1.f - bw) * sigm(so[s][2]) + bw * sigm(dn[s][2]);
        const float bb = (1.f - bw) * sigm(so[s][3]) + bw * sigm(dn[s][3]);
        o_sigma[m] = sigma; o_r[m] = r; o_g[m] = gg; o_b[m] = bb; o_bw[m] = bw;
    }
}

// ---------------- compositing: one wave per ray, float2-vectorized (r12) --------
__global__ __launch_bounds__(256)
void nerf_comp(const float* __restrict__ zv,
               const float* __restrict__ o_sigma, const float* __restrict__ o_r,
               const float* __restrict__ o_g, const float* __restrict__ o_b,
               const float* __restrict__ o_bw, float* __restrict__ out)
{
    const int ray  = blockIdx.x * 4 + (threadIdx.x >> 6);
    const int lane = threadIdx.x & 63;
    const int base = ray * SAMP;

    const f32x2 z01 = *(const f32x2*)(zv + base + 2 * lane);
    const float z0 = z01[0], z1 = z01[1];
    const float z2 = __shfl_down(z0, 1);
    const float d0 = z1 - z0;
    const float d1 = (lane < 63) ? (z2 - z1) : 1e10f;

    const f32x2 sg = *(const f32x2*)(o_sigma + base + 2 * lane);
    const float a0 = 1.0f - expf(-sg[0] * d0);
    const float a1 = 1.0f - expf(-sg[1] * d1);
    const float f0 = 1.0f - a0 + 1e-10f;
    const float f1 = 1.0f - a1 + 1e-10f;

    float incl = f0 * f1;
#pragma unroll
    for (int dlt = 1; dlt < 64; dlt <<= 1) {
        const float t = __shfl_up(incl, dlt);
        if (lane >= dlt) incl *= t;
    }
    float ex = __shfl_up(incl, 1);
    if (lane == 0) ex = 1.0f;

    const float t0 = ex;
    const float t1 = ex * f0;
    const float w0 = a0 * t0, w1 = a1 * t1;

    const f32x2 bw2 = *(const f32x2*)(o_bw + base + 2 * lane);
    f32x2 vw;  vw[0] = w0;                   vw[1] = w1;
    f32x2 vsw; vsw[0] = (1.f - bw2[0]) * w0; vsw[1] = (1.f - bw2[1]) * w1;
    f32x2 vdw; vdw[0] = bw2[0] * w0;         vdw[1] = bw2[1] * w1;
    *(f32x2*)(out + OUT_W  + base + 2 * lane) = vw;
    *(f32x2*)(out + OUT_SW + base + 2 * lane) = vsw;
    *(f32x2*)(out + OUT_DW + base + 2 * lane) = vdw;

    const f32x2 r2 = *(const f32x2*)(o_r + base + 2 * lane);
    const f32x2 g2 = *(const f32x2*)(o_g + base + 2 * lane);
    const f32x2 b2 = *(const f32x2*)(o_b + base + 2 * lane);
    float pr = w0 * r2[0] + w1 * r2[1];
    float pg = w0 * g2[0] + w1 * g2[1];
    float pb = w0 * b2[0] + w1 * b2[1];
    float pd = w0 * z0 + w1 * z1;
#pragma unroll
    for (int dlt = 32; dlt >= 1; dlt >>= 1) {
        pr += __shfl_down(pr, dlt);
        pg += __shfl_down(pg, dlt);
        pb += __shfl_down(pb, dlt);
        pd += __shfl_down(pd, dlt);
    }
    if (lane == 0) {
        out[OUT_RGB + ray * 3 + 0] = pr;
        out[OUT_RGB + ray * 3 + 1] = pg;
        out[OUT_RGB + ray * 3 + 2] = pb;
        out[OUT_DEPTH + ray] = pd;
    }
}

extern "C" void kernel_launch(void* const* d_in, const int* in_sizes, int n_in,
                              void* d_out, int out_size, void* d_ws, size_t ws_size,
                              hipStream_t stream)
{
    const float* points = (const float*)d_in[0];
    const float* dirsv  = (const float*)d_in[1];
    const float* zvals  = (const float*)d_in[2];
    const float* timev  = (const float*)d_in[3];

    const float *sW[5], *sb[5], *dW[5], *db[5];
    if (in_sizes[6] == 99 * 256) {
        for (int i = 0; i < 5; i++) {   // interleaved (sW_i, sb_i, dW_i, db_i)
            sW[i] = (const float*)d_in[4 + 4 * i + 0];
            sb[i] = (const float*)d_in[4 + 4 * i + 1];
            dW[i] = (const float*)d_in[4 + 4 * i + 2];
            db[i] = (const float*)d_in[4 + 4 * i + 3];
        }
    } else {
        for (int i = 0; i < 5; i++) {   // all static then all dynamic
            sW[i] = (const float*)d_in[4 + 2 * i + 0];
            sb[i] = (const float*)d_in[4 + 2 * i + 1];
            dW[i] = (const float*)d_in[14 + 2 * i + 0];
            db[i] = (const float*)d_in[14 + 2 * i + 1];
        }
    }

    // ws layout: bf16 weights (933888 B) then 5 fp32 per-sample arrays (1 MB each)
    short* wt = (short*)d_ws;
    float* ws = (float*)((char*)d_ws + (size_t)WTOT * 2);
    float* o_sigma = ws;
    float* o_r  = ws + (size_t)MTOT * 1;
    float* o_g  = ws + (size_t)MTOT * 2;
    float* o_b  = ws + (size_t)MTOT * 3;
    float* o_bw = ws + (size_t)MTOT * 4;

    prep_weights<<<(WTOT + 255) / 256, 256, 0, stream>>>(
        sW[0], sW[1], sW[2], sW[3], sW[4], dW[0], dW[1], dW[2], dW[3], dW[4], wt);

    nerf_mlp<<<MTOT / BM, 256, 0, stream>>>(points, dirsv, timev, wt,
        sb[0], sb[1], sb[2], sb[3], sb[4], db[0], db[1], db[2], db[3], db[4],
        o_sigma, o_r, o_g, o_b, o_bw);

    nerf_comp<<<RAYS / 4, 256, 0, stream>>>(zvals, o_sigma, o_r, o_g, o_b, o_bw,
                                            (float*)d_out);
}

// Round 13
// 560.975 us; speedup vs baseline: 1.1339x; 1.0046x over previous
//
#include <hip/hip_runtime.h>
#include <math.h>

// FusionNeRF round 15:
//   - r14: 563.5us total / 505.5 mlp (double-angle encoding -40us; VALUBusy
//     21.7->15.2). MfmaUtil 20.5% vs ~90% predicted by the latency model, AND
//     occupancy-insensitive (12w 18.5 / 16w 17.7 / setprio 20.5) -> shared-
//     resource serialization, not latency. Hypothesis: L2 SAME-ADDRESS HERDING:
//     all 4096 blocks read identical weight lines in identical order in
//     near-lockstep (FETCH 7.84MB = 8 XCD x 0.93MB confirms L2-resident).
//   - r15: per-block K-ROTATION: block visits k-slices in order (kk+rot)%KS,
//     rot = blockIdx&7, weights+acts rotated together (dot product identical;
//     fp32 per-accumulator order rotates -> sub-ulp, deterministic). Spreads
//     concurrent requests over 8x more L2 lines. ~9 VALU/kstep addr math.
//     Wait protocol (validated r8/r12/r14) untouched.

#define RAYS 2048
#define SAMP 128
#define MTOT (RAYS * SAMP)
#define HD   256
#define BM   64              // samples per block
#define ES   136             // enc LDS stride (bf16), Kpad=128 (+8 pad, 272B rows)
#define HS   264             // hidden LDS stride (bf16), 256 (+8 pad, 528B rows)

// output float offsets
#define OUT_RGB   0
#define OUT_DEPTH 6144
#define OUT_W     8192
#define OUT_SW    270336
#define OUT_DW    532480

// bf16 weight workspace offsets (elements)
#define SW0 0
#define SW1 32768
#define SW2 98304
#define SW3 163840
#define SW4 229376
#define DW0 233472
#define DW1 266240
#define DW2 331776
#define DW3 397312
#define DW4 462848
#define WTOT 466944

typedef __attribute__((ext_vector_type(8))) short short8;
typedef __attribute__((ext_vector_type(4))) float f32x4;
typedef __attribute__((ext_vector_type(2))) float f32x2;
typedef __attribute__((ext_vector_type(2))) unsigned int uint2v;

__device__ __forceinline__ float sigm(float x) { return 1.0f / (1.0f + expf(-x)); }

__device__ __forceinline__ short f2bf(float f) {   // RNE fp32 -> bf16
    union { float f; unsigned u; } v; v.f = f;
    unsigned r = v.u + 0x7fffu + ((v.u >> 16) & 1u);
    return (short)(r >> 16);
}

// Unmovable memory ops (volatile asm). Counted waits + sched_barrier(0) (rule #18).
#define GLB_LOAD(dst, ptr, imm) \
    asm volatile("global_load_dwordx4 %0, %1, off offset:%c2" \
                 : "=v"(dst) : "v"(ptr), "n"(imm))
#define LDS_READ(dst, addr, imm) \
    asm volatile("ds_read_b128 %0, %1 offset:%c2" \
                 : "=v"(dst) : "v"(addr), "n"(imm))
#define WAITCNT(vm, lg) do { \
    asm volatile("s_waitcnt vmcnt(%c0) lgkmcnt(%c1)" :: "n"(vm), "n"(lg)); \
    __builtin_amdgcn_sched_barrier(0); } while (0)

// Barrier with LDS drain only (validated r5/r8/r12/r14).
__device__ __forceinline__ void bar_lgkm() {
    __builtin_amdgcn_sched_barrier(0);
    asm volatile("s_waitcnt lgkmcnt(0)\n\ts_barrier" ::: "memory");
    __builtin_amdgcn_sched_barrier(0);
}
// Ordering-only barrier (all reads already drained via counted waits).
__device__ __forceinline__ void bar_only() {
    __builtin_amdgcn_sched_barrier(0);
    asm volatile("s_barrier" ::: "memory");
    __builtin_amdgcn_sched_barrier(0);
}

// ---------------- weight prep: W[K][N] fp32 -> Wt[Npad][Kpad] bf16 --------------
// Original 1824-block version (gap ledger: beats both coalesced rewrites).
__device__ __forceinline__ void conv1(const float* __restrict__ src, short* __restrict__ dst,
                                      int local, int K, int N, int Kpad) {
    const int n = local / Kpad, k = local - n * Kpad;
    const float v = (k < K && n < N) ? src[k * N + n] : 0.0f;
    dst[local] = f2bf(v);
}

__global__ __launch_bounds__(256)
void prep_weights(const float* sW0, const float* sW1, const float* sW2,
                  const float* sW3, const float* sW4,
                  const float* dW0, const float* dW1, const float* dW2,
                  const float* dW3, const float* dW4, short* __restrict__ dst)
{
    const int idx = blockIdx.x * 256 + threadIdx.x;
    if (idx >= WTOT) return;
    if      (idx < SW1) conv1(sW0, dst + SW0, idx - SW0,  90, 256, 128);
    else if (idx < SW2) conv1(sW1, dst + SW1, idx - SW1, 256, 256, 256);
    else if (idx < SW3) conv1(sW2, dst + SW2, idx - SW2, 256, 256, 256);
    else if (idx < SW4) conv1(sW3, dst + SW3, idx - SW3, 256, 256, 256);
    else if (idx < DW0) conv1(sW4, dst + SW4, idx - SW4, 256,   4, 256);
    else if (idx < DW1) conv1(dW0, dst + DW0, idx - DW0,  99, 256, 128);
    else if (idx < DW2) conv1(dW1, dst + DW1, idx - DW1, 256, 256, 256);
    else if (idx < DW3) conv1(dW2, dst + DW2, idx - DW2, 256, 256, 256);
    else if (idx < DW4) conv1(dW3, dst + DW3, idx - DW3, 256, 256, 256);
    else                conv1(dW4, dst + DW4, idx - DW4, 256,   5, 256);
}

// ---------------- MFMA dense layer: self-contained asm k-pipeline + k-rotation --
// A-operand = weights Wt[256][K] (global, L2-hot), B-operand = acts [64][AS] (LDS).
// K-slices visited in rotated order (kk+rot)%KSTEPS (weights+acts together) to
// decorrelate cross-block L2 address streams. Entry: issue rk(0),rk(1) weights
// + acts, wait (4,4). Steady: issue rk(kk+1), wait (4,4). Last: wait (0,0) —
// layer self-contained; nothing in flight crosses plain-C code.
template <int KSTEPS, bool RELU, int AS, bool BAR1 = true>
__device__ __forceinline__ void layer256(const short* A,
                                         const short* __restrict__ Wt,
                                         const float* __restrict__ bias,
                                         short* O, int Os, int tid, int rot)
{
    const int w = tid >> 6, lane = tid & 63, qq = lane >> 4, col = lane & 15;
    constexpr int K = KSTEPS * 32;
    constexpr int MSK = KSTEPS - 1;

    const short* wp0 = Wt + (size_t)(w * 64 +  0 + col) * K + qq * 8;
    const short* wp1 = Wt + (size_t)(w * 64 + 16 + col) * K + qq * 8;
    const short* wp2 = Wt + (size_t)(w * 64 + 32 + col) * K + qq * 8;
    const short* wp3 = Wt + (size_t)(w * 64 + 48 + col) * K + qq * 8;
    // LDS byte address (generic shared addr: low 32 bits are the LDS offset)
    const unsigned ab = (unsigned)(size_t)(const void*)A + (unsigned)((col * AS + qq * 8) * 2);

    short8 wa[2][4], ba[2][4];   // ping-pong, all indices compile-time after unroll

    const int rk0 = rot & MSK, rk1 = (rot + 1) & MSK;
    GLB_LOAD(wa[0][0], wp0 + rk0 * 32, 0);
    GLB_LOAD(wa[0][1], wp1 + rk0 * 32, 0);
    GLB_LOAD(wa[0][2], wp2 + rk0 * 32, 0);
    GLB_LOAD(wa[0][3], wp3 + rk0 * 32, 0);
    GLB_LOAD(wa[1][0], wp0 + rk1 * 32, 0);
    GLB_LOAD(wa[1][1], wp1 + rk1 * 32, 0);
    GLB_LOAD(wa[1][2], wp2 + rk1 * 32, 0);
    GLB_LOAD(wa[1][3], wp3 + rk1 * 32, 0);
    LDS_READ(ba[0][0], ab + rk0 * 64, (0 * 16 * AS) * 2);
    LDS_READ(ba[0][1], ab + rk0 * 64, (1 * 16 * AS) * 2);
    LDS_READ(ba[0][2], ab + rk0 * 64, (2 * 16 * AS) * 2);
    LDS_READ(ba[0][3], ab + rk0 * 64, (3 * 16 * AS) * 2);
    LDS_READ(ba[1][0], ab + rk1 * 64, (0 * 16 * AS) * 2);
    LDS_READ(ba[1][1], ab + rk1 * 64, (1 * 16 * AS) * 2);
    LDS_READ(ba[1][2], ab + rk1 * 64, (2 * 16 * AS) * 2);
    LDS_READ(ba[1][3], ab + rk1 * 64, (3 * 16 * AS) * 2);
    WAITCNT(4, 4);   // rk(0) weights+acts ready; rk(1) in flight

    f32x4 acc[4][4];
#pragma unroll
    for (int ft = 0; ft < 4; ft++)
#pragma unroll
        for (int st = 0; st < 4; st++) acc[ft][st] = (f32x4)0.0f;

#pragma unroll
    for (int kk = 0; kk < KSTEPS; kk++) {
        const int c = kk & 1, nx = c ^ 1;
        if (kk > 0 && kk < KSTEPS - 1) {
            const int rkn = (kk + 1 + rot) & MSK;
            GLB_LOAD(wa[nx][0], wp0 + rkn * 32, 0);
            GLB_LOAD(wa[nx][1], wp1 + rkn * 32, 0);
            GLB_LOAD(wa[nx][2], wp2 + rkn * 32, 0);
            GLB_LOAD(wa[nx][3], wp3 + rkn * 32, 0);
            LDS_READ(ba[nx][0], ab + rkn * 64, (0 * 16 * AS) * 2);
            LDS_READ(ba[nx][1], ab + rkn * 64, (1 * 16 * AS) * 2);
            LDS_READ(ba[nx][2], ab + rkn * 64, (2 * 16 * AS) * 2);
            LDS_READ(ba[nx][3], ab + rkn * 64, (3 * 16 * AS) * 2);
            WAITCNT(4, 4);                 // rk(kk) ready; rk(kk+1) in flight
        } else if (kk == KSTEPS - 1) {
            WAITCNT(0, 0);                 // drain: layer self-contained
        }
        __builtin_amdgcn_s_setprio(1);     // T5
#pragma unroll
        for (int ft = 0; ft < 4; ft++)
#pragma unroll
            for (int st = 0; st < 4; st++)
                acc[ft][st] = __builtin_amdgcn_mfma_f32_16x16x32_bf16(
                    wa[c][ft], ba[c][st], acc[ft][st], 0, 0, 0);
        __builtin_amdgcn_s_setprio(0);
    }

    if (BAR1) bar_only();   // waves done reading A (needed only when A aliases O)

#pragma unroll
    for (int ft = 0; ft < 4; ft++) {
        const f32x4 bv = *(const f32x4*)(bias + w * 64 + ft * 16 + qq * 4);
#pragma unroll
        for (int st = 0; st < 4; st++) {
            float v0 = acc[ft][st][0] + bv[0];
            float v1 = acc[ft][st][1] + bv[1];
            float v2 = acc[ft][st][2] + bv[2];
            float v3 = acc[ft][st][3] + bv[3];
            if (RELU) {
                v0 = fmaxf(v0, 0.0f); v1 = fmaxf(v1, 0.0f);
                v2 = fmaxf(v2, 0.0f); v3 = fmaxf(v3, 0.0f);
            }
            unsigned p0, p1;   // RNE pack, matches f2bf
            asm("v_cvt_pk_bf16_f32 %0, %1, %2" : "=v"(p0) : "v"(v0), "v"(v1));
            asm("v_cvt_pk_bf16_f32 %0, %1, %2" : "=v"(p1) : "v"(v2), "v"(v3));
            uint2v pk; pk[0] = p0; pk[1] = p1;
            *(uint2v*)(O + (size_t)(st * 16 + col) * Os + w * 64 + ft * 16 + qq * 4) = pk;
        }
    }
    bar_lgkm();   // O visible to next layer
}

// head (swapped): A-op = head weights Wt[16][256], B-op = acts of wave's 16 samples.
// Plain C — our asm queues are empty here (layers drain), compiler accounting exact.
template <int NV, int OS>
__device__ __forceinline__ void head256(const short* A, int As,
                                        const short* __restrict__ Wt,
                                        const float* __restrict__ bias,
                                        float* Out, int tid)
{
    const int w = tid >> 6, lane = tid & 63, qq = lane >> 4, col = lane & 15;
    f32x4 acc = (f32x4)0.0f;
#pragma unroll
    for (int kk = 0; kk < 8; kk++) {
        short8 a = *(const short8*)(Wt + col * 256 + kk * 32 + qq * 8);
        short8 b = *(const short8*)(A + (size_t)(w * 16 + col) * As + kk * 32 + qq * 8);
        acc = __builtin_amdgcn_mfma_f32_16x16x32_bf16(a, b, acc, 0, 0, 0);
    }
    const int s = w * 16 + col;
    if (qq == 0) {
#pragma unroll
        for (int i = 0; i < 4; i++) Out[s * OS + i] = acc[i] + bias[i];
    } else if (NV == 5 && qq == 1) {
        Out[s * OS + 4] = acc[0] + bias[4];
    }
}

__global__ __launch_bounds__(256, 3)
void nerf_mlp(const float* __restrict__ points, const float* __restrict__ dirsv,
              const float* __restrict__ timev, const short* __restrict__ wt,
              const float* __restrict__ sb0, const float* __restrict__ sb1,
              const float* __restrict__ sb2, const float* __restrict__ sb3,
              const float* __restrict__ sb4,
              const float* __restrict__ db0, const float* __restrict__ db1,
              const float* __restrict__ db2, const float* __restrict__ db3,
              const float* __restrict__ db4,
              float* __restrict__ o_sigma, float* __restrict__ o_r,
              float* __restrict__ o_g, float* __restrict__ o_b,
              float* __restrict__ o_bw)
{
    __shared__ __align__(16) short E[BM][ES];   // 17408 B
    __shared__ __align__(16) short Hb[BM][HS];  // 33792 B
    __shared__ float so[BM][4];                 //  1024 B
    __shared__ float dn[BM][5];                 //  1280 B -> 53504 B => 3 blocks/CU

    const int tid = threadIdx.x;
    const int m0  = blockIdx.x * BM;
    const int rot = blockIdx.x & 7;   // per-block k-rotation (L2 decorrelation)

    // ---- positional encoding -> E. Double-angle recurrence (r14). ----
    for (int idx = tid; idx < 7 * BM; idx += 256) {
        const int c = idx >> 6, s = idx & 63, m = m0 + s;
        float x; int dbase, nb, dstep, coff;
        if (c < 3)      { x = points[m * 3 + c];     E[s][c]      = f2bf(x); dbase = 3 + c;  nb = 10; dstep = 6; coff = 3; }
        else if (c < 6) { x = dirsv[m * 3 + c - 3];  E[s][60 + c] = f2bf(x); dbase = 63 + c; nb = 4;  dstep = 6; coff = 3; }
        else            { x = timev[m];              E[s][90]     = f2bf(x); dbase = 91;     nb = 4;  dstep = 2; coff = 1; }
        float sl = sinf(x), cl = cosf(x);
        int d = dbase;
        E[s][d] = f2bf(sl); E[s][d + coff] = f2bf(cl);
        for (int l = 1; l < nb; l++) {
            const float s2 = 2.0f * sl * cl;
            const float c2 = cl * cl - sl * sl;
            d += dstep;
            E[s][d] = f2bf(s2); E[s][d + coff] = f2bf(c2);
            sl = s2; cl = c2;
        }
    }
    for (int idx = tid; idx < BM * 32; idx += 256) {   // zero pad d=99..127
        const int s = idx >> 5, d = 96 + (idx & 31);
        if (d >= 99) E[s][d] = 0;
    }
    bar_lgkm();

    // ---- static MLP ----
    layer256<4, true, ES, false>(&E[0][0],  wt + SW0, sb0, &Hb[0][0], HS, tid, rot);  // E->Hb: no alias
    layer256<8, true, HS>(&Hb[0][0], wt + SW1, sb1, &Hb[0][0], HS, tid, rot);
    layer256<8, true, HS>(&Hb[0][0], wt + SW2, sb2, &Hb[0][0], HS, tid, rot);
    layer256<8, true, HS>(&Hb[0][0], wt + SW3, sb3, &Hb[0][0], HS, tid, rot);
    head256<4, 4>(&Hb[0][0], HS, wt + SW4, sb4, &so[0][0], tid);
    // (dynamic L0's bar_only orders these head reads of Hb vs its Hb overwrite)

    // ---- dynamic MLP ----
    layer256<4, true, ES>(&E[0][0],  wt + DW0, db0, &Hb[0][0], HS, tid, rot);  // keeps BAR1
    layer256<8, true, HS>(&Hb[0][0], wt + DW1, db1, &Hb[0][0], HS, tid, rot);
    layer256<8, true, HS>(&Hb[0][0], wt + DW2, db2, &Hb[0][0], HS, tid, rot);
    layer256<8, true, HS>(&Hb[0][0], wt + DW3, db3, &Hb[0][0], HS, tid, rot);
    head256<5, 5>(&Hb[0][0], HS, wt + DW4, db4, &dn[0][0], tid);
    bar_lgkm();

    // ---- blend ----
    if (tid < BM) {
        const int s = tid, m = m0 + s;
        const float bw = sigm(dn[s][4]);
        const float sigma = (1.f - bw) * so[s][0] + bw * dn[s][0];
        const float r  = (1.f - bw) * sigm(so[s][1]) + bw * sigm(dn[s][1]);
        const float gg = (1.f - bw) * sigm(so[s][2]) + bw * sigm(dn[s][2]);
        const float bb = (1.f - bw) * sigm(so[s][3]) + bw * sigm(dn[s][3]);
        o_sigma[m] = sigma; o_r[m] = r; o_g[m] = gg; o_b[m] = bb; o_bw[m] = bw;
    }
}

// ---------------- compositing: one wave per ray, float2-vectorized (r12) --------
__global__ __launch_bounds__(256)
void nerf_comp(const float* __restrict__ zv,
               const float* __restrict__ o_sigma, const float* __restrict__ o_r,
               const float* __restrict__ o_g, const float* __restrict__ o_b,
               const float* __restrict__ o_bw, float* __restrict__ out)
{
    const int ray  = blockIdx.x * 4 + (threadIdx.x >> 6);
    const int lane = threadIdx.x & 63;
    const int base = ray * SAMP;

    const f32x2 z01 = *(const f32x2*)(zv + base + 2 * lane);
    const float z0 = z01[0], z1 = z01[1];
    const float z2 = __shfl_down(z0, 1);
    const float d0 = z1 - z0;
    const float d1 = (lane < 63) ? (z2 - z1) : 1e10f;

    const f32x2 sg = *(const f32x2*)(o_sigma + base + 2 * lane);
    const float a0 = 1.0f - expf(-sg[0] * d0);
    const float a1 = 1.0f - expf(-sg[1] * d1);
    const float f0 = 1.0f - a0 + 1e-10f;
    const float f1 = 1.0f - a1 + 1e-10f;

    float incl = f0 * f1;
#pragma unroll
    for (int dlt = 1; dlt < 64; dlt <<= 1) {
        const float t = __shfl_up(incl, dlt);
        if (lane >= dlt) incl *= t;
    }
    float ex = __shfl_up(incl, 1);
    if (lane == 0) ex = 1.0f;

    const float t0 = ex;
    const float t1 = ex * f0;
    const float w0 = a0 * t0, w1 = a1 * t1;

    const f32x2 bw2 = *(const f32x2*)(o_bw + base + 2 * lane);
    f32x2 vw;  vw[0] = w0;                   vw[1] = w1;
    f32x2 vsw; vsw[0] = (1.f - bw2[0]) * w0; vsw[1] = (1.f - bw2[1]) * w1;
    f32x2 vdw; vdw[0] = bw2[0] * w0;         vdw[1] = bw2[1] * w1;
    *(f32x2*)(out + OUT_W  + base + 2 * lane) = vw;
    *(f32x2*)(out + OUT_SW + base + 2 * lane) = vsw;
    *(f32x2*)(out + OUT_DW + base + 2 * lane) = vdw;

    const f32x2 r2 = *(const f32x2*)(o_r + base + 2 * lane);
    const f32x2 g2 = *(const f32x2*)(o_g + base + 2 * lane);
    const f32x2 b2 = *(const f32x2*)(o_b + base + 2 * lane);
    float pr = w0 * r2[0] + w1 * r2[1];
    float pg = w0 * g2[0] + w1 * g2[1];
    float pb = w0 * b2[0] + w1 * b2[1];
    float pd = w0 * z0 + w1 * z1;
#pragma unroll
    for (int dlt = 32; dlt >= 1; dlt >>= 1) {
        pr += __shfl_down(pr, dlt);
        pg += __shfl_down(pg, dlt);
        pb += __shfl_down(pb, dlt);
        pd += __shfl_down(pd, dlt);
    }
    if (lane == 0) {
        out[OUT_RGB + ray * 3 + 0] = pr;
        out[OUT_RGB + ray * 3 + 1] = pg;
        out[OUT_RGB + ray * 3 + 2] = pb;
        out[OUT_DEPTH + ray] = pd;
    }
}

extern "C" void kernel_launch(void* const* d_in, const int* in_sizes, int n_in,
                              void* d_out, int out_size, void* d_ws, size_t ws_size,
                              hipStream_t stream)
{
    const float* points = (const float*)d_in[0];
    const float* dirsv  = (const float*)d_in[1];
    const float* zvals  = (const float*)d_in[2];
    const float* timev  = (const float*)d_in[3];

    const float *sW[5], *sb[5], *dW[5], *db[5];
    if (in_sizes[6] == 99 * 256) {
        for (int i = 0; i < 5; i++) {   // interleaved (sW_i, sb_i, dW_i, db_i)
            sW[i] = (const float*)d_in[4 + 4 * i + 0];
            sb[i] = (const float*)d_in[4 + 4 * i + 1];
            dW[i] = (const float*)d_in[4 + 4 * i + 2];
            db[i] = (const float*)d_in[4 + 4 * i + 3];
        }
    } else {
        for (int i = 0; i < 5; i++) {   // all static then all dynamic
            sW[i] = (const float*)d_in[4 + 2 * i + 0];
            sb[i] = (const float*)d_in[4 + 2 * i + 1];
            dW[i] = (const float*)d_in[14 + 2 * i + 0];
            db[i] = (const float*)d_in[14 + 2 * i + 1];
        }
    }

    // ws layout: bf16 weights (933888 B) then 5 fp32 per-sample arrays (1 MB each)
    short* wt = (short*)d_ws;
    float* ws = (float*)((char*)d_ws + (size_t)WTOT * 2);
    float* o_sigma = ws;
    float* o_r  = ws + (size_t)MTOT * 1;
    float* o_g  = ws + (size_t)MTOT * 2;
    float* o_b  = ws + (size_t)MTOT * 3;
    float* o_bw = ws + (size_t)MTOT * 4;

    prep_weights<<<(WTOT + 255) / 256, 256, 0, stream>>>(
        sW[0], sW[1], sW[2], sW[3], sW[4], dW[0], dW[1], dW[2], dW[3], dW[4], wt);

    nerf_mlp<<<MTOT / BM, 256, 0, stream>>>(points, dirsv, timev, wt,
        sb[0], sb[1], sb[2], sb[3], sb[4], db[0], db[1], db[2], db[3], db[4],
        o_sigma, o_r, o_g, o_b, o_bw);

    nerf_comp<<<RAYS / 4, 256, 0, stream>>>(zvals, o_sigma, o_r, o_g, o_b, o_bw,
                                            (float*)d_out);
}

// Round 14
// 456.146 us; speedup vs baseline: 1.3945x; 1.2298x over previous
//
#include <hip/hip_runtime.h>
#include <math.h>

// FusionNeRF round 16:
//   - r15 (k-rotation) NULL -> herding-by-order falsified. Unified model: per-CU
//     L2 weight-return BW binds. Waves own disjoint features -> every wave
//     streams 4KB/kstep; full-MFMA demand 205 B/cyc/CU vs ~56 supply -> ceiling
//     27% (measured 20.7). Explains r9/r10/r15 nulls + occupancy-insensitivity.
//   - r16: BM=128. Same wave geometry (64 feats/wave) but 8 sample-frags ->
//     each weight fetch feeds 2x MFMAs; total weight traffic 3.8->1.9 GB;
//     ceiling ~53%. acc[4][8]=128 AGPR; 2-phase kstep keeps ba[2][4] small.
//     LDS 107KB -> 1 block/CU (occupancy ~12% is EXPECTED). Self-contained
//     counted-wait protocol preserved. Rotation dropped (null).

#define RAYS 2048
#define SAMP 128
#define MTOT (RAYS * SAMP)
#define HD   256
#define BM   128             // samples per block (r16: doubled)
#define ES   136             // enc LDS stride (bf16), Kpad=128 (+8 pad)
#define HS   264             // hidden LDS stride (bf16), 256 (+8 pad)

// output float offsets
#define OUT_RGB   0
#define OUT_DEPTH 6144
#define OUT_W     8192
#define OUT_SW    270336
#define OUT_DW    532480

// bf16 weight workspace offsets (elements)
#define SW0 0
#define SW1 32768
#define SW2 98304
#define SW3 163840
#define SW4 229376
#define DW0 233472
#define DW1 266240
#define DW2 331776
#define DW3 397312
#define DW4 462848
#define WTOT 466944

typedef __attribute__((ext_vector_type(8))) short short8;
typedef __attribute__((ext_vector_type(4))) float f32x4;
typedef __attribute__((ext_vector_type(2))) float f32x2;
typedef __attribute__((ext_vector_type(2))) unsigned int uint2v;

__device__ __forceinline__ float sigm(float x) { return 1.0f / (1.0f + expf(-x)); }

__device__ __forceinline__ short f2bf(float f) {   // RNE fp32 -> bf16
    union { float f; unsigned u; } v; v.f = f;
    unsigned r = v.u + 0x7fffu + ((v.u >> 16) & 1u);
    return (short)(r >> 16);
}

// Unmovable memory ops (volatile asm). Counted waits + sched_barrier(0) (rule #18).
#define GLB_LOAD(dst, ptr, imm) \
    asm volatile("global_load_dwordx4 %0, %1, off offset:%c2" \
                 : "=v"(dst) : "v"(ptr), "n"(imm))
#define LDS_READ(dst, addr, imm) \
    asm volatile("ds_read_b128 %0, %1 offset:%c2" \
                 : "=v"(dst) : "v"(addr), "n"(imm))
#define WAITCNT(vm, lg) do { \
    asm volatile("s_waitcnt vmcnt(%c0) lgkmcnt(%c1)" :: "n"(vm), "n"(lg)); \
    __builtin_amdgcn_sched_barrier(0); } while (0)

// Barrier with LDS drain only (validated r5/r8/r12/r14).
__device__ __forceinline__ void bar_lgkm() {
    __builtin_amdgcn_sched_barrier(0);
    asm volatile("s_waitcnt lgkmcnt(0)\n\ts_barrier" ::: "memory");
    __builtin_amdgcn_sched_barrier(0);
}
// Ordering-only barrier (all reads already drained via counted waits).
__device__ __forceinline__ void bar_only() {
    __builtin_amdgcn_sched_barrier(0);
    asm volatile("s_barrier" ::: "memory");
    __builtin_amdgcn_sched_barrier(0);
}

// ---------------- weight prep: W[K][N] fp32 -> Wt[Npad][Kpad] bf16 --------------
__device__ __forceinline__ void conv1(const float* __restrict__ src, short* __restrict__ dst,
                                      int local, int K, int N, int Kpad) {
    const int n = local / Kpad, k = local - n * Kpad;
    const float v = (k < K && n < N) ? src[k * N + n] : 0.0f;
    dst[local] = f2bf(v);
}

__global__ __launch_bounds__(256)
void prep_weights(const float* sW0, const float* sW1, const float* sW2,
                  const float* sW3, const float* sW4,
                  const float* dW0, const float* dW1, const float* dW2,
                  const float* dW3, const float* dW4, short* __restrict__ dst)
{
    const int idx = blockIdx.x * 256 + threadIdx.x;
    if (idx >= WTOT) return;
    if      (idx < SW1) conv1(sW0, dst + SW0, idx - SW0,  90, 256, 128);
    else if (idx < SW2) conv1(sW1, dst + SW1, idx - SW1, 256, 256, 256);
    else if (idx < SW3) conv1(sW2, dst + SW2, idx - SW2, 256, 256, 256);
    else if (idx < SW4) conv1(sW3, dst + SW3, idx - SW3, 256, 256, 256);
    else if (idx < DW0) conv1(sW4, dst + SW4, idx - SW4, 256,   4, 256);
    else if (idx < DW1) conv1(dW0, dst + DW0, idx - DW0,  99, 256, 128);
    else if (idx < DW2) conv1(dW1, dst + DW1, idx - DW1, 256, 256, 256);
    else if (idx < DW3) conv1(dW2, dst + DW2, idx - DW2, 256, 256, 256);
    else if (idx < DW4) conv1(dW3, dst + DW3, idx - DW3, 256, 256, 256);
    else                conv1(dW4, dst + DW4, idx - DW4, 256,   5, 256);
}

// ---------------- MFMA dense layer: 64feat x 128samp per wave, 2-phase kstep ----
// A-operand = weights Wt[256][K] (global, L2-hot), B-operand = acts [128][AS] (LDS).
// Wave w owns feats [64w,64w+64); samples split into 8 st-frags (2 phases of 4).
// Phase 0 of kk: issue W(kk+1) + A(kk,h1); wait (4,4); MFMA st0-3.
// Phase 1 of kk: issue A(kk+1,h0); wait (4,4); MFMA st4-7.
// Last kstep: (0,4) then (0,0) — self-contained; nothing crosses plain-C code.
template <int KSTEPS, bool RELU, int AS, bool BAR1 = true>
__device__ __forceinline__ void layer256(const short* A,
                                         const short* __restrict__ Wt,
                                         const float* __restrict__ bias,
                                         short* O, int Os, int tid)
{
    const int w = tid >> 6, lane = tid & 63, qq = lane >> 4, col = lane & 15;
    constexpr int K = KSTEPS * 32;

    const short* wp0 = Wt + (size_t)(w * 64 +  0 + col) * K + qq * 8;
    const short* wp1 = Wt + (size_t)(w * 64 + 16 + col) * K + qq * 8;
    const short* wp2 = Wt + (size_t)(w * 64 + 32 + col) * K + qq * 8;
    const short* wp3 = Wt + (size_t)(w * 64 + 48 + col) * K + qq * 8;
    // LDS byte address (generic shared addr: low 32 bits are the LDS offset)
    const unsigned ab = (unsigned)(size_t)(const void*)A + (unsigned)((col * AS + qq * 8) * 2);

    short8 wa[2][4], ba[2][4];   // wa: kstep ping-pong; ba: phase ping-pong

    // entry: W(0) + A(0, half0)
    GLB_LOAD(wa[0][0], wp0, 0);
    GLB_LOAD(wa[0][1], wp1, 0);
    GLB_LOAD(wa[0][2], wp2, 0);
    GLB_LOAD(wa[0][3], wp3, 0);
    LDS_READ(ba[0][0], ab, (0 * 16 * AS) * 2);
    LDS_READ(ba[0][1], ab, (1 * 16 * AS) * 2);
    LDS_READ(ba[0][2], ab, (2 * 16 * AS) * 2);
    LDS_READ(ba[0][3], ab, (3 * 16 * AS) * 2);

    f32x4 acc[4][8];   // [ft][st] — 128 AGPR, const-indexed after unroll
#pragma unroll
    for (int ft = 0; ft < 4; ft++)
#pragma unroll
        for (int st = 0; st < 8; st++) acc[ft][st] = (f32x4)0.0f;

#pragma unroll
    for (int kk = 0; kk < KSTEPS; kk++) {
        const int c = kk & 1, nx = c ^ 1;
        // ---- phase 0: feats x st0-3 ----
        if (kk + 1 < KSTEPS) {
            GLB_LOAD(wa[nx][0], wp0, (kk + 1) * 64);
            GLB_LOAD(wa[nx][1], wp1, (kk + 1) * 64);
            GLB_LOAD(wa[nx][2], wp2, (kk + 1) * 64);
            GLB_LOAD(wa[nx][3], wp3, (kk + 1) * 64);
        }
        LDS_READ(ba[1][0], ab, (4 * 16 * AS) * 2 + kk * 64);   // h1 of kk
        LDS_READ(ba[1][1], ab, (5 * 16 * AS) * 2 + kk * 64);
        LDS_READ(ba[1][2], ab, (6 * 16 * AS) * 2 + kk * 64);
        LDS_READ(ba[1][3], ab, (7 * 16 * AS) * 2 + kk * 64);
        if (kk + 1 < KSTEPS) WAITCNT(4, 4);   // W(kk),h0(kk) ready; W(kk+1),h1(kk) fly
        else                 WAITCNT(0, 4);   // last: all W drained; h1 flying
        __builtin_amdgcn_s_setprio(1);
#pragma unroll
        for (int ft = 0; ft < 4; ft++)
#pragma unroll
            for (int st = 0; st < 4; st++)
                acc[ft][st] = __builtin_amdgcn_mfma_f32_16x16x32_bf16(
                    wa[c][ft], ba[0][st], acc[ft][st], 0, 0, 0);
        __builtin_amdgcn_s_setprio(0);
        // ---- phase 1: feats x st4-7 ----
        if (kk + 1 < KSTEPS) {
            LDS_READ(ba[0][0], ab, (0 * 16 * AS) * 2 + (kk + 1) * 64);  // h0 of kk+1
            LDS_READ(ba[0][1], ab, (1 * 16 * AS) * 2 + (kk + 1) * 64);
            LDS_READ(ba[0][2], ab, (2 * 16 * AS) * 2 + (kk + 1) * 64);
            LDS_READ(ba[0][3], ab, (3 * 16 * AS) * 2 + (kk + 1) * 64);
            WAITCNT(4, 4);    // h1(kk) ready; W(kk+1) + h0(kk+1) flying
        } else {
            WAITCNT(0, 0);    // drain: layer self-contained
        }
        __builtin_amdgcn_s_setprio(1);
#pragma unroll
        for (int ft = 0; ft < 4; ft++)
#pragma unroll
            for (int st = 0; st < 4; st++)
                acc[ft][4 + st] = __builtin_amdgcn_mfma_f32_16x16x32_bf16(
                    wa[c][ft], ba[1][st], acc[ft][4 + st], 0, 0, 0);
        __builtin_amdgcn_s_setprio(0);
    }

    if (BAR1) bar_only();   // waves done reading A (needed only when A aliases O)

#pragma unroll
    for (int ft = 0; ft < 4; ft++) {
        const f32x4 bv = *(const f32x4*)(bias + w * 64 + ft * 16 + qq * 4);
#pragma unroll
        for (int st = 0; st < 8; st++) {
            float v0 = acc[ft][st][0] + bv[0];
            float v1 = acc[ft][st][1] + bv[1];
            float v2 = acc[ft][st][2] + bv[2];
            float v3 = acc[ft][st][3] + bv[3];
            if (RELU) {
                v0 = fmaxf(v0, 0.0f); v1 = fmaxf(v1, 0.0f);
                v2 = fmaxf(v2, 0.0f); v3 = fmaxf(v3, 0.0f);
            }
            unsigned p0, p1;   // RNE pack, matches f2bf
            asm("v_cvt_pk_bf16_f32 %0, %1, %2" : "=v"(p0) : "v"(v0), "v"(v1));
            asm("v_cvt_pk_bf16_f32 %0, %1, %2" : "=v"(p1) : "v"(v2), "v"(v3));
            uint2v pk; pk[0] = p0; pk[1] = p1;
            *(uint2v*)(O + (size_t)(st * 16 + col) * Os + w * 64 + ft * 16 + qq * 4) = pk;
        }
    }
    bar_lgkm();   // O visible to next layer
}

// head (swapped): two 64-sample halves; wave w handles samples g*64 + w*16 + col.
// Plain C — our asm queues are empty here (layers drain), compiler accounting exact.
template <int NV, int OS>
__device__ __forceinline__ void head256(const short* A, int As,
                                        const short* __restrict__ Wt,
                                        const float* __restrict__ bias,
                                        float* Out, int tid)
{
    const int w = tid >> 6, lane = tid & 63, qq = lane >> 4, col = lane & 15;
#pragma unroll
    for (int g = 0; g < 2; g++) {
        const int s = g * 64 + w * 16 + col;
        f32x4 acc = (f32x4)0.0f;
#pragma unroll
        for (int kk = 0; kk < 8; kk++) {
            short8 a = *(const short8*)(Wt + col * 256 + kk * 32 + qq * 8);
            short8 b = *(const short8*)(A + (size_t)s * As + kk * 32 + qq * 8);
            acc = __builtin_amdgcn_mfma_f32_16x16x32_bf16(a, b, acc, 0, 0, 0);
        }
        if (qq == 0) {
#pragma unroll
            for (int i = 0; i < 4; i++) Out[s * OS + i] = acc[i] + bias[i];
        } else if (NV == 5 && qq == 1) {
            Out[s * OS + 4] = acc[0] + bias[4];
        }
    }
}

__global__ __launch_bounds__(256, 1)
void nerf_mlp(const float* __restrict__ points, const float* __restrict__ dirsv,
              const float* __restrict__ timev, const short* __restrict__ wt,
              const float* __restrict__ sb0, const float* __restrict__ sb1,
              const float* __restrict__ sb2, const float* __restrict__ sb3,
              const float* __restrict__ sb4,
              const float* __restrict__ db0, const float* __restrict__ db1,
              const float* __restrict__ db2, const float* __restrict__ db3,
              const float* __restrict__ db4,
              float* __restrict__ o_sigma, float* __restrict__ o_r,
              float* __restrict__ o_g, float* __restrict__ o_b,
              float* __restrict__ o_bw)
{
    __shared__ __align__(16) short E[BM][ES];   // 34816 B
    __shared__ __align__(16) short Hb[BM][HS];  // 67584 B
    __shared__ float so[BM][4];                 //  2048 B
    __shared__ float dn[BM][5];                 //  2560 B -> 107008 B => 1 block/CU

    const int tid = threadIdx.x;
    const int m0  = blockIdx.x * BM;

    // ---- positional encoding -> E. Double-angle recurrence (r14), BM=128. ----
    for (int idx = tid; idx < 7 * BM; idx += 256) {
        const int c = idx >> 7, s = idx & 127, m = m0 + s;   // c wave-uniform
        float x; int dbase, nb, dstep, coff;
        if (c < 3)      { x = points[m * 3 + c];     E[s][c]      = f2bf(x); dbase = 3 + c;  nb = 10; dstep = 6; coff = 3; }
        else if (c < 6) { x = dirsv[m * 3 + c - 3];  E[s][60 + c] = f2bf(x); dbase = 63 + c; nb = 4;  dstep = 6; coff = 3; }
        else            { x = timev[m];              E[s][90]     = f2bf(x); dbase = 91;     nb = 4;  dstep = 2; coff = 1; }
        float sl = sinf(x), cl = cosf(x);
        int d = dbase;
        E[s][d] = f2bf(sl); E[s][d + coff] = f2bf(cl);
        for (int l = 1; l < nb; l++) {
            const float s2 = 2.0f * sl * cl;
            const float c2 = cl * cl - sl * sl;
            d += dstep;
            E[s][d] = f2bf(s2); E[s][d + coff] = f2bf(c2);
            sl = s2; cl = c2;
        }
    }
    for (int idx = tid; idx < BM * 32; idx += 256) {   // zero pad d=99..127
        const int s = idx >> 5, d = 96 + (idx & 31);
        if (d >= 99) E[s][d] = 0;
    }
    bar_lgkm();

    // ---- static MLP ----
    layer256<4, true, ES, false>(&E[0][0],  wt + SW0, sb0, &Hb[0][0], HS, tid);  // E->Hb: no alias
    layer256<8, true, HS>(&Hb[0][0], wt + SW1, sb1, &Hb[0][0], HS, tid);
    layer256<8, true, HS>(&Hb[0][0], wt + SW2, sb2, &Hb[0][0], HS, tid);
    layer256<8, true, HS>(&Hb[0][0], wt + SW3, sb3, &Hb[0][0], HS, tid);
    head256<4, 4>(&Hb[0][0], HS, wt + SW4, sb4, &so[0][0], tid);
    // (dynamic L0's bar_only orders these head reads of Hb vs its Hb overwrite)

    // ---- dynamic MLP ----
    layer256<4, true, ES>(&E[0][0],  wt + DW0, db0, &Hb[0][0], HS, tid);  // keeps BAR1
    layer256<8, true, HS>(&Hb[0][0], wt + DW1, db1, &Hb[0][0], HS, tid);
    layer256<8, true, HS>(&Hb[0][0], wt + DW2, db2, &Hb[0][0], HS, tid);
    layer256<8, true, HS>(&Hb[0][0], wt + DW3, db3, &Hb[0][0], HS, tid);
    head256<5, 5>(&Hb[0][0], HS, wt + DW4, db4, &dn[0][0], tid);
    bar_lgkm();

    // ---- blend ----
    if (tid < BM) {
        const int s = tid, m = m0 + s;
        const float bw = sigm(dn[s][4]);
        const float sigma = (1.f - bw) * so[s][0] + bw * dn[s][0];
        const float r  = (1.f - bw) * sigm(so[s][1]) + bw * sigm(dn[s][1]);
        const float gg = (1.f - bw) * sigm(so[s][2]) + bw * sigm(dn[s][2]);
        const float bb = (1.f - bw) * sigm(so[s][3]) + bw * sigm(dn[s][3]);
        o_sigma[m] = sigma; o_r[m] = r; o_g[m] = gg; o_b[m] = bb; o_bw[m] = bw;
    }
}

// ---------------- compositing: one wave per ray, float2-vectorized (r12) --------
__global__ __launch_bounds__(256)
void nerf_comp(const float* __restrict__ zv,
               const float* __restrict__ o_sigma, const float* __restrict__ o_r,
               const float* __restrict__ o_g, const float* __restrict__ o_b,
               const float* __restrict__ o_bw, float* __restrict__ out)
{
    const int ray  = blockIdx.x * 4 + (threadIdx.x >> 6);
    const int lane = threadIdx.x & 63;
    const int base = ray * SAMP;

    const f32x2 z01 = *(const f32x2*)(zv + base + 2 * lane);
    const float z0 = z01[0], z1 = z01[1];
    const float z2 = __shfl_down(z0, 1);
    const float d0 = z1 - z0;
    const float d1 = (lane < 63) ? (z2 - z1) : 1e10f;

    const f32x2 sg = *(const f32x2*)(o_sigma + base + 2 * lane);
    const float a0 = 1.0f - expf(-sg[0] * d0);
    const float a1 = 1.0f - expf(-sg[1] * d1);
    const float f0 = 1.0f - a0 + 1e-10f;
    const float f1 = 1.0f - a1 + 1e-10f;

    float incl = f0 * f1;
#pragma unroll
    for (int dlt = 1; dlt < 64; dlt <<= 1) {
        const float t = __shfl_up(incl, dlt);
        if (lane >= dlt) incl *= t;
    }
    float ex = __shfl_up(incl, 1);
    if (lane == 0) ex = 1.0f;

    const float t0 = ex;
    const float t1 = ex * f0;
    const float w0 = a0 * t0, w1 = a1 * t1;

    const f32x2 bw2 = *(const f32x2*)(o_bw + base + 2 * lane);
    f32x2 vw;  vw[0] = w0;                   vw[1] = w1;
    f32x2 vsw; vsw[0] = (1.f - bw2[0]) * w0; vsw[1] = (1.f - bw2[1]) * w1;
    f32x2 vdw; vdw[0] = bw2[0] * w0;         vdw[1] = bw2[1] * w1;
    *(f32x2*)(out + OUT_W  + base + 2 * lane) = vw;
    *(f32x2*)(out + OUT_SW + base + 2 * lane) = vsw;
    *(f32x2*)(out + OUT_DW + base + 2 * lane) = vdw;

    const f32x2 r2 = *(const f32x2*)(o_r + base + 2 * lane);
    const f32x2 g2 = *(const f32x2*)(o_g + base + 2 * lane);
    const f32x2 b2 = *(const f32x2*)(o_b + base + 2 * lane);
    float pr = w0 * r2[0] + w1 * r2[1];
    float pg = w0 * g2[0] + w1 * g2[1];
    float pb = w0 * b2[0] + w1 * b2[1];
    float pd = w0 * z0 + w1 * z1;
#pragma unroll
    for (int dlt = 32; dlt >= 1; dlt >>= 1) {
        pr += __shfl_down(pr, dlt);
        pg += __shfl_down(pg, dlt);
        pb += __shfl_down(pb, dlt);
        pd += __shfl_down(pd, dlt);
    }
    if (lane == 0) {
        out[OUT_RGB + ray * 3 + 0] = pr;
        out[OUT_RGB + ray * 3 + 1] = pg;
        out[OUT_RGB + ray * 3 + 2] = pb;
        out[OUT_DEPTH + ray] = pd;
    }
}

extern "C" void kernel_launch(void* const* d_in, const int* in_sizes, int n_in,
                              void* d_out, int out_size, void* d_ws, size_t ws_size,
                              hipStream_t stream)
{
    const float* points = (const float*)d_in[0];
    const float* dirsv  = (const float*)d_in[1];
    const float* zvals  = (const float*)d_in[2];
    const float* timev  = (const float*)d_in[3];

    const float *sW[5], *sb[5], *dW[5], *db[5];
    if (in_sizes[6] == 99 * 256) {
        for (int i = 0; i < 5; i++) {   // interleaved (sW_i, sb_i, dW_i, db_i)
            sW[i] = (const float*)d_in[4 + 4 * i + 0];
            sb[i] = (const float*)d_in[4 + 4 * i + 1];
            dW[i] = (const float*)d_in[4 + 4 * i + 2];
            db[i] = (const float*)d_in[4 + 4 * i + 3];
        }
    } else {
        for (int i = 0; i < 5; i++) {   // all static then all dynamic
            sW[i] = (const float*)d_in[4 + 2 * i + 0];
            sb[i] = (const float*)d_in[4 + 2 * i + 1];
            dW[i] = (const float*)d_in[14 + 2 * i + 0];
            db[i] = (const float*)d_in[14 + 2 * i + 1];
        }
    }

    // ws layout: bf16 weights (933888 B) then 5 fp32 per-sample arrays (1 MB each)
    short* wt = (short*)d_ws;
    float* ws = (float*)((char*)d_ws + (size_t)WTOT * 2);
    float* o_sigma = ws;
    float* o_r  = ws + (size_t)MTOT * 1;
    float* o_g  = ws + (size_t)MTOT * 2;
    float* o_b  = ws + (size_t)MTOT * 3;
    float* o_bw = ws + (size_t)MTOT * 4;

    prep_weights<<<(WTOT + 255) / 256, 256, 0, stream>>>(
        sW[0], sW[1], sW[2], sW[3], sW[4], dW[0], dW[1], dW[2], dW[3], dW[4], wt);

    nerf_mlp<<<MTOT / BM, 256, 0, stream>>>(points, dirsv, timev, wt,
        sb[0], sb[1], sb[2], sb[3], sb[4], db[0], db[1], db[2], db[3], db[4],
        o_sigma, o_r, o_g, o_b, o_bw);

    nerf_comp<<<RAYS / 4, 256, 0, stream>>>(zvals, o_sigma, o_r, o_g, o_b, o_bw,
                                            (float*)d_out);
}